// Round 7
// baseline (158.169 us; speedup 1.0000x reference)
//
#include <hip/hip_runtime.h>
#include <hip/hip_bf16.h>
#include <math.h>

#define BB 4
#define CC 256
#define HH 64
#define WW 64
#define HW 4096
#define PH 68
#define PW 68
#define COUT 256
#define OFFC 216
#define KTOT 2304
#define NCHUNK 72

typedef __attribute__((ext_vector_type(4))) float f32x4;
typedef __attribute__((ext_vector_type(8))) short s16x8;
typedef __attribute__((ext_vector_type(8))) unsigned short u16x8;
typedef __attribute__((ext_vector_type(2))) unsigned int u32x2;
typedef __attribute__((ext_vector_type(4))) unsigned int u32x4;

__device__ __forceinline__ unsigned short f2bf(float f) {
    unsigned int u = __float_as_uint(f);
    return (unsigned short)((u + 0x7fffu + ((u >> 16) & 1u)) >> 16);
}
__device__ __forceinline__ float bflo(unsigned int u) { return __uint_as_float(u << 16); }
__device__ __forceinline__ float bfhi(unsigned int u) { return __uint_as_float(u & 0xffff0000u); }
__device__ __forceinline__ unsigned int pkbf(float a, float b) {
    __hip_bfloat162 h = __float22bfloat162_rn(make_float2(a, b));
    unsigned int r;
    __builtin_memcpy(&r, &h, 4);
    return r;
}

// barrier WITHOUT vmcnt drain: LDS ordering only; global loads stay in flight.
#define BAR()                                               \
    {                                                       \
        asm volatile("s_waitcnt lgkmcnt(0)" ::: "memory");  \
        __builtin_amdgcn_sched_barrier(0);                  \
        __builtin_amdgcn_s_barrier();                       \
        __builtin_amdgcn_sched_barrier(0);                  \
    }

// ---------- pack main weight (linear): wp[t][oc][kk], t=dg*9+tap, c=dg*32+kk
__global__ __launch_bounds__(256) void pack_w_main(const float* __restrict__ w,
                                                   unsigned short* __restrict__ wp) {
    int idx = blockIdx.x * 256 + threadIdx.x;
    int t = idx >> 13, r = idx & 8191;
    int oc = r >> 5, kk = r & 31;
    int dg = t / 9, tap = t - dg * 9;
    int c = dg * 32 + kk;
    wp[idx] = f2bf(w[((size_t)oc * CC + c) * 9 + tap]);
}

// ---------- pack offset weight (pad 216->256), t = tap*8+cg
__global__ __launch_bounds__(256) void pack_w_off(const float* __restrict__ w,
                                                  unsigned short* __restrict__ wp) {
    int idx = blockIdx.x * 256 + threadIdx.x;
    int t = idx >> 13, r = idx & 8191;
    int oc = r >> 5, kk = r & 31;
    int tap = t >> 3, cg = t & 7;
    int c = cg * 32 + kk;
    float v = (oc < OFFC) ? w[((size_t)oc * CC + c) * 9 + tap] : 0.f;
    wp[idx] = f2bf(v);
}

// ---------- NCHW f32 -> padded NHWC bf16 (zero ring of 2), LDS-transposed coalesced
__global__ __launch_bounds__(256) void pad_tr2(const float* __restrict__ srcx,
                                               const float* __restrict__ srce,
                                               unsigned short* __restrict__ dx_,
                                               unsigned short* __restrict__ de_) {
    const float* src = blockIdx.y ? srce : srcx;
    unsigned short* dst = blockIdx.y ? de_ : dx_;
    int blk = blockIdx.x;
    int b = blk / PH, yp = blk % PH;
    int y = yp - 2;
    unsigned short* drow = dst + ((size_t)b * PH + yp) * PW * CC;
    int tid = threadIdx.x;
    if ((unsigned)y >= (unsigned)HH) {
        for (int i = tid; i < PW * CC / 8; i += 256) *(u16x8*)&drow[(size_t)i * 8] = (u16x8)0;
        return;
    }
    __shared__ float tile[64][65];
    int lane = tid & 63, w = tid >> 6;
    int oct = tid & 7, xi = tid >> 3;
    const float* srow = src + (size_t)b * CC * HW + (size_t)y * WW;
    for (int chunk = 0; chunk < 4; chunk++) {
        __syncthreads();
#pragma unroll
        for (int i = 0; i < 16; i++) {
            int c = chunk * 64 + w * 16 + i;
            tile[w * 16 + i][lane] = srow[(size_t)c * HW + lane];
        }
        __syncthreads();
#pragma unroll
        for (int xq = 0; xq < 3; xq++) {
            int xp = xq * 32 + xi;
            if (xp < PW) {
                int x = xp - 2;
                u16x8 v = (u16x8)0;
                if ((unsigned)x < (unsigned)WW) {
#pragma unroll
                    for (int e = 0; e < 8; e++) v[e] = f2bf(tile[oct * 8 + e][x]);
                }
                *(u16x8*)&drow[(size_t)xp * CC + chunk * 64 + oct * 8] = v;
            }
        }
    }
}

// ---------- prep: raw {dy,dx,mraw,.} -> {packed idx, bf16 w00|w01, w10|w11, 0}, IN PLACE
__global__ __launch_bounds__(256) void prep_off(float* __restrict__ om) {
    int idx = blockIdx.x * 256 + threadIdx.x;
    const int per_b = NCHUNK * HW;
    int b = idx / per_b;
    int r = idx - b * per_b;
    int t = r >> 12, p = r & 4095;
    int y = p >> 6, x = p & 63;
    f32x4 raw = *((const f32x4*)om + idx);
    int dg = (t * 57) >> 9;
    int tap = t - dg * 9;
    int ky = tap / 3, kx = tap - ky * 3;
    float mv = 1.f / (1.f + __expf(-raw[2]));
    float py = (float)(y + ky - 1) + raw[0];
    float px = (float)(x + kx - 1) + raw[1];
    float y0f = floorf(py), x0f = floorf(px);
    float fy = py - y0f, fx = px - x0f;
    int yp0 = min(max((int)y0f + 2, 0), PH - 1);
    int yp1 = min(max((int)y0f + 3, 0), PH - 1);
    int xp0 = min(max((int)x0f + 2, 0), PW - 1);
    int xp1 = min(max((int)x0f + 3, 0), PW - 1);
    unsigned int iv = (unsigned int)(yp0 * PW + xp0) | ((unsigned int)(xp1 - xp0) << 13) |
                      ((unsigned int)(yp1 - yp0) << 14);
    float w00 = (1.f - fy) * (1.f - fx) * mv;
    float w01 = (1.f - fy) * fx * mv;
    float w10 = fy * (1.f - fx) * mv;
    float w11 = fy * fx * mv;
    u32x4 o;
    o[0] = iv;
    o[1] = pkbf(w00, w01);
    o[2] = pkbf(w10, w11);
    o[3] = 0;
    *((u32x4*)om + idx) = o;
}

// shared GEMM geometry: block = 128oc x 64px, 8 waves (wm 0..3, wn 0..1), wave = 32oc x 32px.
// A: global->reg, 1 iter ahead. B: LDS dbuf [2][64px][32ch], 16B-slot XOR swizzle (slot ^= px&3).

#define ALOAD(WPP, T, AF)                                                                   \
    {                                                                                       \
        const unsigned short* wt_ =                                                         \
            WPP + (size_t)(T) * 8192 + (size_t)(ocbase + wm * 32 + r16) * 32 + lg * 8;      \
        AF[0] = *(const s16x8*)&wt_[0];                                                     \
        AF[1] = *(const s16x8*)&wt_[512];                                                   \
    }

#define MFMA4R(AC, BUF)                                                                     \
    {                                                                                       \
        int sw_ = (lg ^ (r16 & 3)) * 8;                                                     \
        s16x8 b0 = *(const s16x8*)&sB[BUF][wn * 32 + r16][sw_];                             \
        s16x8 b1 = *(const s16x8*)&sB[BUF][wn * 32 + 16 + r16][sw_];                        \
        acc[0][0] = __builtin_amdgcn_mfma_f32_16x16x32_bf16(AC[0], b0, acc[0][0], 0, 0, 0); \
        acc[0][1] = __builtin_amdgcn_mfma_f32_16x16x32_bf16(AC[0], b1, acc[0][1], 0, 0, 0); \
        acc[1][0] = __builtin_amdgcn_mfma_f32_16x16x32_bf16(AC[1], b0, acc[1][0], 0, 0, 0); \
        acc[1][1] = __builtin_amdgcn_mfma_f32_16x16x32_bf16(AC[1], b1, acc[1][1], 0, 0, 0); \
    }

#define SBSLOT (((grp >> 1) ^ (pxg & 3)) * 8 + (grp & 1) * 4)

// ======================================================================
// offset conv
// ======================================================================
__global__ __launch_bounds__(512, 4) void off_mfma(const unsigned short* __restrict__ eT,
                                                   const unsigned short* __restrict__ wp,
                                                   const float* __restrict__ off_b,
                                                   float* __restrict__ om4) {
    __shared__ __align__(16) unsigned short sB[2][64][32];
    int bx = blockIdx.x;
    int b = bx >> 6, y = bx & 63;
    int ocbase = blockIdx.y * 128;
    int tid = threadIdx.x;
    int lane = tid & 63;
    int w = tid >> 6;
    int wm = w & 3, wn = w >> 2;
    int r16 = lane & 15, lg = lane >> 4;
    int pxg = tid >> 3, grp = tid & 7;

    const unsigned short* eb = eT + (size_t)b * PH * PW * CC;

    f32x4 acc[2][2];
#pragma unroll
    for (int mi = 0; mi < 2; mi++)
#pragma unroll
        for (int ni = 0; ni < 2; ni++) acc[mi][ni] = (f32x4)0.f;

    s16x8 aA[2], aB[2];

#define OF_LOADB(T, BN)                                                                      \
    {                                                                                        \
        int tap_ = (T) >> 3, cg_ = (T) & 7;                                                  \
        int ky_ = tap_ / 3, kx_ = tap_ - ky_ * 3;                                            \
        BN = *(const u32x2*)&eb[(size_t)((y + ky_ + 1) * PW + (pxg + kx_ + 1)) * CC +        \
                                cg_ * 32 + grp * 4];                                         \
    }
#define OF_IT(T, AC, AN, BUF)                                                                \
    {                                                                                        \
        u32x2 bn;                                                                            \
        if ((T) + 1 < NCHUNK) {                                                              \
            ALOAD(wp, (T) + 1, AN)                                                           \
            OF_LOADB((T) + 1, bn)                                                            \
        }                                                                                    \
        MFMA4R(AC, BUF)                                                                      \
        if ((T) + 1 < NCHUNK) *(u32x2*)&sB[(BUF) ^ 1][pxg][SBSLOT] = bn;                     \
        BAR()                                                                                \
    }

    {
        u32x2 b0v;
        OF_LOADB(0, b0v)
        *(u32x2*)&sB[0][pxg][SBSLOT] = b0v;
        ALOAD(wp, 0, aA)
        BAR()
    }
    for (int t = 0; t < NCHUNK; t += 2) {
        OF_IT(t, aA, aB, 0)
        OF_IT(t + 1, aB, aA, 1)
    }

    float* omb4 = om4 + (size_t)b * NCHUNK * HW * 4;
#pragma unroll
    for (int mi = 0; mi < 2; mi++) {
#pragma unroll
        for (int ni = 0; ni < 2; ni++) {
#pragma unroll
            for (int j = 0; j < 4; j++) {
                int oc = ocbase + wm * 32 + mi * 16 + lg * 4 + j;
                if (oc < OFFC) {
                    int pxo = wn * 32 + ni * 16 + r16;
                    float v = acc[mi][ni][j] + off_b[oc];
                    int dg, tap, comp;
                    if (oc < 144) {
                        dg = oc / 18;
                        int rr = oc - dg * 18;
                        tap = rr >> 1;
                        comp = rr & 1;
                    } else {
                        int o2 = oc - 144;
                        dg = o2 / 9;
                        tap = o2 - dg * 9;
                        comp = 2;
                    }
                    omb4[((size_t)(dg * 9 + tap) * HW + y * WW + pxo) * 4 + comp] = v;
                }
            }
        }
    }
}

// ======================================================================
// fused deformable sampling + main conv
// ======================================================================
__global__ __launch_bounds__(512, 4) void dconv_mfma(const unsigned short* __restrict__ xT,
                                                     const float* __restrict__ omP,
                                                     const unsigned short* __restrict__ wp,
                                                     const float* __restrict__ bias,
                                                     float* __restrict__ out) {
    __shared__ __align__(16) unsigned short sB[2][64][32];
    int bx = blockIdx.x;
    int b = bx >> 6, y = bx & 63;
    int ocbase = blockIdx.y * 128;
    int tid = threadIdx.x;
    int lane = tid & 63;
    int w = tid >> 6;
    int wm = w & 3, wn = w >> 2;
    int r16 = lane & 15, lg = lane >> 4;
    int pxg = tid >> 3, grp = tid & 7;
    int yx = y * WW + pxg;

    const unsigned short* xb = xT + (size_t)b * PH * PW * CC;
    const float* omPb = omP + (size_t)b * NCHUNK * HW * 4;

    f32x4 acc[2][2];
#pragma unroll
    for (int mi = 0; mi < 2; mi++)
#pragma unroll
        for (int ni = 0; ni < 2; ni++) acc[mi][ni] = (f32x4)0.f;

    s16x8 aA[2], aB[2];

#define DC_OML(T) (*(const u32x4*)(omPb + ((size_t)(T)*HW + yx) * 4))

#define DC_GATHER(T, OM, G00, G01, G10, G11)                                  \
    {                                                                         \
        int dg_ = ((T) * 57) >> 9;                                            \
        unsigned int iv_ = OM[0];                                             \
        int o00_ = (int)(iv_ & 8191u) << 8;                                   \
        int dxe_ = (int)((iv_ >> 13) & 1u) << 8;                              \
        int dye_ = ((iv_ >> 14) & 1u) ? (PW * CC) : 0;                        \
        const unsigned short* p_ = xb + dg_ * 32 + grp * 4;                   \
        G00 = *(const u32x2*)(p_ + o00_);                                     \
        G01 = *(const u32x2*)(p_ + o00_ + dxe_);                              \
        G10 = *(const u32x2*)(p_ + o00_ + dye_);                              \
        G11 = *(const u32x2*)(p_ + o00_ + dye_ + dxe_);                       \
    }
#define DC_FIN(OM, G00, G01, G10, G11, BUF)                                                        \
    {                                                                                              \
        float w00 = bflo(OM[1]), w01 = bfhi(OM[1]);                                                \
        float w10 = bflo(OM[2]), w11 = bfhi(OM[2]);                                                \
        float v0 = w00 * bflo(G00[0]) + w01 * bflo(G01[0]) + w10 * bflo(G10[0]) + w11 * bflo(G11[0]); \
        float v1 = w00 * bfhi(G00[0]) + w01 * bfhi(G01[0]) + w10 * bfhi(G10[0]) + w11 * bfhi(G11[0]); \
        float v2 = w00 * bflo(G00[1]) + w01 * bflo(G01[1]) + w10 * bflo(G10[1]) + w11 * bflo(G11[1]); \
        float v3 = w00 * bfhi(G00[1]) + w01 * bfhi(G01[1]) + w10 * bfhi(G10[1]) + w11 * bfhi(G11[1]); \
        u32x2 pk_;                                                                                 \
        pk_[0] = pkbf(v0, v1);                                                                     \
        pk_[1] = pkbf(v2, v3);                                                                     \
        *(u32x2*)&sB[BUF][pxg][SBSLOT] = pk_;                                                      \
    }
#define DC_IT(T, AC, AN, OMC, OMN, BUF)                                       \
    {                                                                         \
        u32x2 g00, g01, g10, g11;                                             \
        if ((T) + 1 < NCHUNK) {                                               \
            ALOAD(wp, (T) + 1, AN)                                            \
            DC_GATHER((T) + 1, OMC, g00, g01, g10, g11)                       \
        }                                                                     \
        if ((T) + 2 < NCHUNK) OMN = DC_OML((T) + 2);                          \
        MFMA4R(AC, BUF)                                                       \
        if ((T) + 1 < NCHUNK) DC_FIN(OMC, g00, g01, g10, g11, (BUF) ^ 1)      \
        BAR()                                                                 \
    }

    u32x4 omC, omN;
    {
        u32x4 om0 = DC_OML(0);
        u32x2 g00, g01, g10, g11;
        DC_GATHER(0, om0, g00, g01, g10, g11)
        ALOAD(wp, 0, aA)
        omC = DC_OML(1);
        DC_FIN(om0, g00, g01, g10, g11, 0)
        BAR()
    }
    for (int t = 0; t < NCHUNK; t += 2) {
        DC_IT(t, aA, aB, omC, omN, 0)
        DC_IT(t + 1, aB, aA, omN, omC, 1)
    }

#pragma unroll
    for (int mi = 0; mi < 2; mi++) {
#pragma unroll
        for (int ni = 0; ni < 2; ni++) {
#pragma unroll
            for (int j = 0; j < 4; j++) {
                int oc = ocbase + wm * 32 + mi * 16 + lg * 4 + j;
                int pxo = wn * 32 + ni * 16 + r16;
                out[(size_t)(b * COUT + oc) * HW + y * WW + pxo] = acc[mi][ni][j] + bias[oc];
            }
        }
    }
}

extern "C" void kernel_launch(void* const* d_in, const int* in_sizes, int n_in,
                              void* d_out, int out_size, void* d_ws, size_t ws_size,
                              hipStream_t stream) {
    const float* x = (const float*)d_in[0];
    const float* extra_feat = (const float*)d_in[1];
    const float* weight = (const float*)d_in[2];
    const float* bias = (const float*)d_in[3];
    const float* off_w = (const float*)d_in[4];
    const float* off_b = (const float*)d_in[5];
    float* out = (float*)d_out;

    float* omP = (float*)d_ws;
    unsigned short* wpm = (unsigned short*)(omP + (size_t)BB * NCHUNK * HW * 4);
    unsigned short* wpo = wpm + (size_t)KTOT * COUT;
    unsigned short* xT = wpo + (size_t)KTOT * COUT;
    unsigned short* eT = xT + (size_t)BB * PH * PW * CC;

    pack_w_main<<<(KTOT * COUT) / 256, 256, 0, stream>>>(weight, wpm);
    pack_w_off<<<(KTOT * COUT) / 256, 256, 0, stream>>>(off_w, wpo);
    pad_tr2<<<dim3(BB * PH, 2), 256, 0, stream>>>(x, extra_feat, xT, eT);

    off_mfma<<<dim3(BB * HH, 2), 512, 0, stream>>>(eT, wpo, off_b, omP);
    prep_off<<<(BB * NCHUNK * HW) / 256, 256, 0, stream>>>(omP);
    dconv_mfma<<<dim3(BB * HH, 2), 512, 0, stream>>>(xT, omP, wpm, bias, out);
}

// Round 8
// 147.250 us; speedup vs baseline: 1.0741x; 1.0741x over previous
//
#include <hip/hip_runtime.h>
#include <hip/hip_bf16.h>
#include <math.h>

#define BB 4
#define CC 256
#define HH 64
#define WW 64
#define HW 4096
#define PH 68
#define PW 68
#define COUT 256
#define OFFC 216
#define KTOT 2304
#define NCHUNK 72

typedef __attribute__((ext_vector_type(4))) float f32x4;
typedef __attribute__((ext_vector_type(8))) short s16x8;
typedef __attribute__((ext_vector_type(8))) unsigned short u16x8;
typedef __attribute__((ext_vector_type(4))) unsigned int u32x4;

__device__ __forceinline__ unsigned short f2bf(float f) {
    unsigned int u = __float_as_uint(f);
    return (unsigned short)((u + 0x7fffu + ((u >> 16) & 1u)) >> 16);
}
__device__ __forceinline__ float bflo(unsigned int u) { return __uint_as_float(u << 16); }
__device__ __forceinline__ float bfhi(unsigned int u) { return __uint_as_float(u & 0xffff0000u); }
__device__ __forceinline__ unsigned int pkbf(float a, float b) {
    __hip_bfloat162 h = __float22bfloat162_rn(make_float2(a, b));
    unsigned int r;
    __builtin_memcpy(&r, &h, 4);
    return r;
}
__device__ __forceinline__ void glds16(const void* g, void* l) {
    __builtin_amdgcn_global_load_lds((const __attribute__((address_space(1))) unsigned int*)g,
                                     (__attribute__((address_space(3))) unsigned int*)l, 16, 0, 0);
}

// ---------- pack main weight, k-swizzled per oc row:
// wp[t][oc][s*8+e] = w[oc][c = dg*32 + ((s^(oc&3))*8+e)][tap],  t = dg*9+tap
__global__ __launch_bounds__(256) void pack_w_main(const float* __restrict__ w,
                                                   unsigned short* __restrict__ wp) {
    int idx = blockIdx.x * 256 + threadIdx.x;
    int t = idx >> 13, r = idx & 8191;
    int oc = r >> 5, s = (r >> 3) & 3, e = r & 7;
    int kk = ((s ^ (oc & 3)) << 3) | e;
    int dg = t / 9, tap = t - dg * 9;
    int c = dg * 32 + kk;
    wp[idx] = f2bf(w[((size_t)oc * CC + c) * 9 + tap]);
}

// ---------- pack offset weight (pad 216->256), t = tap*8+cg, same swizzle
__global__ __launch_bounds__(256) void pack_w_off(const float* __restrict__ w,
                                                  unsigned short* __restrict__ wp) {
    int idx = blockIdx.x * 256 + threadIdx.x;
    int t = idx >> 13, r = idx & 8191;
    int oc = r >> 5, s = (r >> 3) & 3, e = r & 7;
    int kk = ((s ^ (oc & 3)) << 3) | e;
    int tap = t >> 3, cg = t & 7;
    int c = cg * 32 + kk;
    float v = (oc < OFFC) ? w[((size_t)oc * CC + c) * 9 + tap] : 0.f;
    wp[idx] = f2bf(v);
}

// ---------- NCHW f32 -> padded NHWC bf16 (zero ring of 2), LDS-transposed coalesced
__global__ __launch_bounds__(256) void pad_tr2(const float* __restrict__ srcx,
                                               const float* __restrict__ srce,
                                               unsigned short* __restrict__ dx_,
                                               unsigned short* __restrict__ de_) {
    const float* src = blockIdx.y ? srce : srcx;
    unsigned short* dst = blockIdx.y ? de_ : dx_;
    int blk = blockIdx.x;
    int b = blk / PH, yp = blk % PH;
    int y = yp - 2;
    unsigned short* drow = dst + ((size_t)b * PH + yp) * PW * CC;
    int tid = threadIdx.x;
    if ((unsigned)y >= (unsigned)HH) {
        for (int i = tid; i < PW * CC / 8; i += 256) *(u16x8*)&drow[(size_t)i * 8] = (u16x8)0;
        return;
    }
    __shared__ float tile[64][65];
    int lane = tid & 63, w = tid >> 6;
    int oct = tid & 7, xi = tid >> 3;
    const float* srow = src + (size_t)b * CC * HW + (size_t)y * WW;
    for (int chunk = 0; chunk < 4; chunk++) {
        __syncthreads();
#pragma unroll
        for (int i = 0; i < 16; i++) {
            int c = chunk * 64 + w * 16 + i;
            tile[w * 16 + i][lane] = srow[(size_t)c * HW + lane];
        }
        __syncthreads();
#pragma unroll
        for (int xq = 0; xq < 3; xq++) {
            int xp = xq * 32 + xi;
            if (xp < PW) {
                int x = xp - 2;
                u16x8 v = (u16x8)0;
                if ((unsigned)x < (unsigned)WW) {
#pragma unroll
                    for (int e = 0; e < 8; e++) v[e] = f2bf(tile[oct * 8 + e][x]);
                }
                *(u16x8*)&drow[(size_t)xp * CC + chunk * 64 + oct * 8] = v;
            }
        }
    }
}

// ---------- prep: raw {dy,dx,mraw,.} -> {packed idx, bf16 w00|w01, w10|w11, 0}, IN PLACE
__global__ __launch_bounds__(256) void prep_off(float* __restrict__ om) {
    int idx = blockIdx.x * 256 + threadIdx.x;
    const int per_b = NCHUNK * HW;
    int b = idx / per_b;
    int r = idx - b * per_b;
    int t = r >> 12, p = r & 4095;
    int y = p >> 6, x = p & 63;
    f32x4 raw = *((const f32x4*)om + idx);
    int dg = (t * 57) >> 9;
    int tap = t - dg * 9;
    int ky = tap / 3, kx = tap - ky * 3;
    float mv = 1.f / (1.f + __expf(-raw[2]));
    float py = (float)(y + ky - 1) + raw[0];
    float px = (float)(x + kx - 1) + raw[1];
    float y0f = floorf(py), x0f = floorf(px);
    float fy = py - y0f, fx = px - x0f;
    int yp0 = min(max((int)y0f + 2, 0), PH - 1);
    int yp1 = min(max((int)y0f + 3, 0), PH - 1);
    int xp0 = min(max((int)x0f + 2, 0), PW - 1);
    int xp1 = min(max((int)x0f + 3, 0), PW - 1);
    unsigned int iv = (unsigned int)(yp0 * PW + xp0) | ((unsigned int)(xp1 - xp0) << 13) |
                      ((unsigned int)(yp1 - yp0) << 14);
    float w00 = (1.f - fy) * (1.f - fx) * mv;
    float w01 = (1.f - fy) * fx * mv;
    float w10 = fy * (1.f - fx) * mv;
    float w11 = fy * fx * mv;
    u32x4 o;
    o[0] = iv;
    o[1] = pkbf(w00, w01);
    o[2] = pkbf(w10, w11);
    o[3] = 0;
    *((u32x4*)om + idx) = o;
}

// ======================================================================
// GEMM geometry (both convs): block = 512 thr = 8 waves.
// Tile: M=256 oc (full), N=32 px, K-step 32. Grid: (b*64 rows, 2 px-halves).
// Wave w owns oc [w*32, w*32+32); all waves share the 2KB B-tile.
// A: 16KB/iter via global_load_lds (pack pre-swizzled, LDS linear, read swizzled).
// B: sampled/loaded by VALU, 4B/thread, XOR-swizzled writes (2-way, free).
// ======================================================================

// A stage: wave wu stages 1024 elems (2 x glds16)
#define A_STAGE(WPP, T, BUF)                                                     \
    {                                                                            \
        const unsigned short* s1_ = WPP + (size_t)(T) * 8192 + wu * 1024 + lane * 8; \
        glds16(s1_, &sA[BUF][wu * 1024]);                                        \
        glds16(s1_ + 512, &sA[BUF][wu * 1024 + 512]);                            \
    }

// 4 MFMA: wave tile 32oc x 32px
#define MFMA4(BUF)                                                                           \
    {                                                                                        \
        int sw_ = (lg ^ (r16 & 3)) << 3;                                                     \
        s16x8 a0 = *(const s16x8*)&sA[BUF][(w * 32 + r16) * 32 + sw_];                       \
        s16x8 a1 = *(const s16x8*)&sA[BUF][(w * 32 + 16 + r16) * 32 + sw_];                  \
        s16x8 b0 = *(const s16x8*)&sB[BUF][r16 * 32 + sw_];                                  \
        s16x8 b1 = *(const s16x8*)&sB[BUF][(16 + r16) * 32 + sw_];                           \
        acc[0][0] = __builtin_amdgcn_mfma_f32_16x16x32_bf16(a0, b0, acc[0][0], 0, 0, 0);     \
        acc[0][1] = __builtin_amdgcn_mfma_f32_16x16x32_bf16(a0, b1, acc[0][1], 0, 0, 0);     \
        acc[1][0] = __builtin_amdgcn_mfma_f32_16x16x32_bf16(a1, b0, acc[1][0], 0, 0, 0);     \
        acc[1][1] = __builtin_amdgcn_mfma_f32_16x16x32_bf16(a1, b1, acc[1][1], 0, 0, 0);     \
    }

// B write slot for thread (px_l, ch2): 2-way-free banks, matches MFMA read XOR
#define BSLOT (px_l * 32 + ((((ch2 >> 2) ^ (px_l & 3))) << 3) + (ch2 & 3) * 2)

// ======================================================================
// offset conv
// ======================================================================
__global__ __launch_bounds__(512, 4) void off_mfma(const unsigned short* __restrict__ eT,
                                                   const unsigned short* __restrict__ wp,
                                                   const float* __restrict__ off_b,
                                                   float* __restrict__ om4) {
    __shared__ __align__(16) unsigned short sA[2][8192];
    __shared__ __align__(16) unsigned short sB[2][1024];
    int bx = blockIdx.x;
    int b = bx >> 6, y = bx & 63;
    int pxh = blockIdx.y;
    int tid = threadIdx.x;
    int lane = tid & 63;
    int w = tid >> 6;
    int wu = __builtin_amdgcn_readfirstlane(w);
    int r16 = lane & 15, lg = lane >> 4;
    int px_l = tid >> 4, ch2 = tid & 15;
    int pxg = pxh * 32 + px_l;

    const unsigned short* eb = eT + (size_t)b * PH * PW * CC;

    f32x4 acc[2][2];
#pragma unroll
    for (int mi = 0; mi < 2; mi++)
#pragma unroll
        for (int ni = 0; ni < 2; ni++) acc[mi][ni] = (f32x4)0.f;

#define OF_B(T, BV)                                                                         \
    {                                                                                       \
        int tap_ = (T) >> 3, cg_ = (T) & 7;                                                 \
        int ky_ = tap_ / 3, kx_ = tap_ - ky_ * 3;                                           \
        BV = *(const unsigned int*)&eb[(size_t)((y + ky_ + 1) * PW + (pxg + kx_ + 1)) * CC + \
                                       cg_ * 32 + ch2 * 2];                                 \
    }
#define OF_IT(T, BUF)                                                     \
    {                                                                     \
        __syncthreads();                                                  \
        unsigned int bv_ = 0;                                             \
        if ((T) + 1 < NCHUNK) {                                           \
            A_STAGE(wp, (T) + 1, (BUF) ^ 1)                               \
            OF_B((T) + 1, bv_)                                            \
        }                                                                 \
        MFMA4(BUF)                                                        \
        if ((T) + 1 < NCHUNK) *(unsigned int*)&sB[(BUF) ^ 1][BSLOT] = bv_; \
    }

    {
        A_STAGE(wp, 0, 0)
        unsigned int bv0;
        OF_B(0, bv0)
        *(unsigned int*)&sB[0][BSLOT] = bv0;
    }
    for (int t = 0; t < NCHUNK; t += 2) {
        OF_IT(t, 0)
        OF_IT(t + 1, 1)
    }

    float* omb4 = om4 + (size_t)b * NCHUNK * HW * 4;
#pragma unroll
    for (int mi = 0; mi < 2; mi++) {
#pragma unroll
        for (int ni = 0; ni < 2; ni++) {
#pragma unroll
            for (int j = 0; j < 4; j++) {
                int oc = w * 32 + mi * 16 + lg * 4 + j;
                if (oc < OFFC) {
                    int pxo = pxh * 32 + ni * 16 + r16;
                    float v = acc[mi][ni][j] + off_b[oc];
                    int dg, tap, comp;
                    if (oc < 144) {
                        dg = oc / 18;
                        int rr = oc - dg * 18;
                        tap = rr >> 1;
                        comp = rr & 1;
                    } else {
                        int o2 = oc - 144;
                        dg = o2 / 9;
                        tap = o2 - dg * 9;
                        comp = 2;
                    }
                    omb4[((size_t)(dg * 9 + tap) * HW + y * WW + pxo) * 4 + comp] = v;
                }
            }
        }
    }
}

// ======================================================================
// fused deformable sampling + main conv
// ======================================================================
__global__ __launch_bounds__(512, 4) void dconv_mfma(const unsigned short* __restrict__ xT,
                                                     const float* __restrict__ omP,
                                                     const unsigned short* __restrict__ wp,
                                                     const float* __restrict__ bias,
                                                     float* __restrict__ out) {
    __shared__ __align__(16) unsigned short sA[2][8192];
    __shared__ __align__(16) unsigned short sB[2][1024];
    int bx = blockIdx.x;
    int b = bx >> 6, y = bx & 63;
    int pxh = blockIdx.y;
    int tid = threadIdx.x;
    int lane = tid & 63;
    int w = tid >> 6;
    int wu = __builtin_amdgcn_readfirstlane(w);
    int r16 = lane & 15, lg = lane >> 4;
    int px_l = tid >> 4, ch2 = tid & 15;
    int yx = y * WW + pxh * 32 + px_l;

    const unsigned short* xb = xT + (size_t)b * PH * PW * CC;
    const float* omPb = omP + (size_t)b * NCHUNK * HW * 4;

    f32x4 acc[2][2];
#pragma unroll
    for (int mi = 0; mi < 2; mi++)
#pragma unroll
        for (int ni = 0; ni < 2; ni++) acc[mi][ni] = (f32x4)0.f;

#define DC_OML(T) (*(const u32x4*)(omPb + ((size_t)(T)*HW + yx) * 4))

    // gather 4 corners, 2 channels (4B) each
#define DC_G(T, OM, G00, G01, G10, G11)                                   \
    {                                                                     \
        int dg_ = ((T) * 57) >> 9;                                        \
        unsigned int iv_ = OM[0];                                         \
        int o00_ = (int)(iv_ & 8191u) << 8;                               \
        int dxe_ = (int)((iv_ >> 13) & 1u) << 8;                          \
        int dye_ = ((iv_ >> 14) & 1u) ? (PW * CC) : 0;                    \
        const unsigned short* p_ = xb + dg_ * 32 + ch2 * 2;               \
        G00 = *(const unsigned int*)(p_ + o00_);                          \
        G01 = *(const unsigned int*)(p_ + o00_ + dxe_);                   \
        G10 = *(const unsigned int*)(p_ + o00_ + dye_);                   \
        G11 = *(const unsigned int*)(p_ + o00_ + dye_ + dxe_);            \
    }
#define DC_FIN(OM, G00, G01, G10, G11, BUF)                                               \
    {                                                                                     \
        float w00 = bflo(OM[1]), w01 = bfhi(OM[1]);                                       \
        float w10 = bflo(OM[2]), w11 = bfhi(OM[2]);                                       \
        float v0 = w00 * bflo(G00) + w01 * bflo(G01) + w10 * bflo(G10) + w11 * bflo(G11); \
        float v1 = w00 * bfhi(G00) + w01 * bfhi(G01) + w10 * bfhi(G10) + w11 * bfhi(G11); \
        *(unsigned int*)&sB[BUF][BSLOT] = pkbf(v0, v1);                                   \
    }
#define DC_IT(T, BUF, OMC, OMN)                                           \
    {                                                                     \
        __syncthreads();                                                  \
        unsigned int g00, g01, g10, g11;                                  \
        if ((T) + 1 < NCHUNK) {                                           \
            A_STAGE(wp, (T) + 1, (BUF) ^ 1)                               \
            DC_G((T) + 1, OMC, g00, g01, g10, g11)                        \
        }                                                                 \
        if ((T) + 2 < NCHUNK) OMN = DC_OML((T) + 2);                      \
        MFMA4(BUF)                                                        \
        if ((T) + 1 < NCHUNK) DC_FIN(OMC, g00, g01, g10, g11, (BUF) ^ 1)  \
    }

    u32x4 omC, omN;
    {
        A_STAGE(wp, 0, 0)
        u32x4 om0 = DC_OML(0);
        unsigned int g00, g01, g10, g11;
        DC_G(0, om0, g00, g01, g10, g11)
        omC = DC_OML(1);
        DC_FIN(om0, g00, g01, g10, g11, 0)
    }
    for (int t = 0; t < NCHUNK; t += 2) {
        DC_IT(t, 0, omC, omN)
        DC_IT(t + 1, 1, omN, omC)
    }

#pragma unroll
    for (int mi = 0; mi < 2; mi++) {
#pragma unroll
        for (int ni = 0; ni < 2; ni++) {
#pragma unroll
            for (int j = 0; j < 4; j++) {
                int oc = w * 32 + mi * 16 + lg * 4 + j;
                int pxo = pxh * 32 + ni * 16 + r16;
                out[(size_t)(b * COUT + oc) * HW + y * WW + pxo] = acc[mi][ni][j] + bias[oc];
            }
        }
    }
}

extern "C" void kernel_launch(void* const* d_in, const int* in_sizes, int n_in,
                              void* d_out, int out_size, void* d_ws, size_t ws_size,
                              hipStream_t stream) {
    const float* x = (const float*)d_in[0];
    const float* extra_feat = (const float*)d_in[1];
    const float* weight = (const float*)d_in[2];
    const float* bias = (const float*)d_in[3];
    const float* off_w = (const float*)d_in[4];
    const float* off_b = (const float*)d_in[5];
    float* out = (float*)d_out;

    float* omP = (float*)d_ws;
    unsigned short* wpm = (unsigned short*)(omP + (size_t)BB * NCHUNK * HW * 4);
    unsigned short* wpo = wpm + (size_t)KTOT * COUT;
    unsigned short* xT = wpo + (size_t)KTOT * COUT;
    unsigned short* eT = xT + (size_t)BB * PH * PW * CC;

    pack_w_main<<<(KTOT * COUT) / 256, 256, 0, stream>>>(weight, wpm);
    pack_w_off<<<(KTOT * COUT) / 256, 256, 0, stream>>>(off_w, wpo);
    pad_tr2<<<dim3(BB * PH, 2), 256, 0, stream>>>(x, extra_feat, xT, eT);

    off_mfma<<<dim3(BB * HH, 2), 512, 0, stream>>>(eT, wpo, off_b, omP);
    prep_off<<<(BB * NCHUNK * HW) / 256, 256, 0, stream>>>(omP);
    dconv_mfma<<<dim3(BB * HH, 2), 512, 0, stream>>>(xT, omP, wpm, bias, out);
}

// Round 9
// 131.903 us; speedup vs baseline: 1.1991x; 1.1164x over previous
//
#include <hip/hip_runtime.h>
#include <hip/hip_bf16.h>
#include <math.h>

#define BB 4
#define CC 256
#define HH 64
#define WW 64
#define HW 4096
#define PH 68
#define PW 68
#define COUT 256
#define OFFC 216
#define KTOT 2304
#define NCHUNK 72

typedef __attribute__((ext_vector_type(4))) float f32x4;
typedef __attribute__((ext_vector_type(8))) short s16x8;
typedef __attribute__((ext_vector_type(8))) unsigned short u16x8;
typedef __attribute__((ext_vector_type(4))) unsigned int u32x4;

__device__ __forceinline__ unsigned short f2bf(float f) {
    unsigned int u = __float_as_uint(f);
    return (unsigned short)((u + 0x7fffu + ((u >> 16) & 1u)) >> 16);
}
__device__ __forceinline__ float bflo(unsigned int u) { return __uint_as_float(u << 16); }
__device__ __forceinline__ float bfhi(unsigned int u) { return __uint_as_float(u & 0xffff0000u); }
__device__ __forceinline__ unsigned int pkbf(float a, float b) {
    __hip_bfloat162 h = __float22bfloat162_rn(make_float2(a, b));
    unsigned int r;
    __builtin_memcpy(&r, &h, 4);
    return r;
}
__device__ __forceinline__ void glds16(const void* g, void* l) {
    __builtin_amdgcn_global_load_lds((const __attribute__((address_space(1))) unsigned int*)g,
                                     (__attribute__((address_space(3))) unsigned int*)l, 16, 0, 0);
}

// ---------- pack main weight, k-swizzled per oc row (2-row granular):
// wp[t][oc][s*8+e] = w[oc][c = dg*32 + ((s^((oc>>1)&3))*8+e)][tap],  t = dg*9+tap
__global__ __launch_bounds__(256) void pack_w_main(const float* __restrict__ w,
                                                   unsigned short* __restrict__ wp) {
    int idx = blockIdx.x * 256 + threadIdx.x;
    int t = idx >> 13, r = idx & 8191;
    int oc = r >> 5, s = (r >> 3) & 3, e = r & 7;
    int kk = ((s ^ ((oc >> 1) & 3)) << 3) | e;
    int dg = t / 9, tap = t - dg * 9;
    int c = dg * 32 + kk;
    wp[idx] = f2bf(w[((size_t)oc * CC + c) * 9 + tap]);
}

// ---------- pack offset weight (pad 216->256), t = tap*8+cg, same swizzle
__global__ __launch_bounds__(256) void pack_w_off(const float* __restrict__ w,
                                                  unsigned short* __restrict__ wp) {
    int idx = blockIdx.x * 256 + threadIdx.x;
    int t = idx >> 13, r = idx & 8191;
    int oc = r >> 5, s = (r >> 3) & 3, e = r & 7;
    int kk = ((s ^ ((oc >> 1) & 3)) << 3) | e;
    int tap = t >> 3, cg = t & 7;
    int c = cg * 32 + kk;
    float v = (oc < OFFC) ? w[((size_t)oc * CC + c) * 9 + tap] : 0.f;
    wp[idx] = f2bf(v);
}

// ---------- NCHW f32 -> padded NHWC bf16 (zero ring of 2), LDS-transposed coalesced
__global__ __launch_bounds__(256) void pad_tr2(const float* __restrict__ srcx,
                                               const float* __restrict__ srce,
                                               unsigned short* __restrict__ dx_,
                                               unsigned short* __restrict__ de_) {
    const float* src = blockIdx.y ? srce : srcx;
    unsigned short* dst = blockIdx.y ? de_ : dx_;
    int blk = blockIdx.x;
    int b = blk / PH, yp = blk % PH;
    int y = yp - 2;
    unsigned short* drow = dst + ((size_t)b * PH + yp) * PW * CC;
    int tid = threadIdx.x;
    if ((unsigned)y >= (unsigned)HH) {
        for (int i = tid; i < PW * CC / 8; i += 256) *(u16x8*)&drow[(size_t)i * 8] = (u16x8)0;
        return;
    }
    __shared__ float tile[64][65];
    int lane = tid & 63, w = tid >> 6;
    int oct = tid & 7, xi = tid >> 3;
    const float* srow = src + (size_t)b * CC * HW + (size_t)y * WW;
    for (int chunk = 0; chunk < 4; chunk++) {
        __syncthreads();
#pragma unroll
        for (int i = 0; i < 16; i++) {
            int c = chunk * 64 + w * 16 + i;
            tile[w * 16 + i][lane] = srow[(size_t)c * HW + lane];
        }
        __syncthreads();
#pragma unroll
        for (int xq = 0; xq < 3; xq++) {
            int xp = xq * 32 + xi;
            if (xp < PW) {
                int x = xp - 2;
                u16x8 v = (u16x8)0;
                if ((unsigned)x < (unsigned)WW) {
#pragma unroll
                    for (int e = 0; e < 8; e++) v[e] = f2bf(tile[oct * 8 + e][x]);
                }
                *(u16x8*)&drow[(size_t)xp * CC + chunk * 64 + oct * 8] = v;
            }
        }
    }
}

// ---------- prep: raw {dy,dx,mraw,.} -> {packed idx, bf16 w00|w01, w10|w11, 0}, IN PLACE
__global__ __launch_bounds__(256) void prep_off(float* __restrict__ om) {
    int idx = blockIdx.x * 256 + threadIdx.x;
    const int per_b = NCHUNK * HW;
    int b = idx / per_b;
    int r = idx - b * per_b;
    int t = r >> 12, p = r & 4095;
    int y = p >> 6, x = p & 63;
    f32x4 raw = *((const f32x4*)om + idx);
    int dg = (t * 57) >> 9;
    int tap = t - dg * 9;
    int ky = tap / 3, kx = tap - ky * 3;
    float mv = 1.f / (1.f + __expf(-raw[2]));
    float py = (float)(y + ky - 1) + raw[0];
    float px = (float)(x + kx - 1) + raw[1];
    float y0f = floorf(py), x0f = floorf(px);
    float fy = py - y0f, fx = px - x0f;
    int yp0 = min(max((int)y0f + 2, 0), PH - 1);
    int yp1 = min(max((int)y0f + 3, 0), PH - 1);
    int xp0 = min(max((int)x0f + 2, 0), PW - 1);
    int xp1 = min(max((int)x0f + 3, 0), PW - 1);
    unsigned int iv = (unsigned int)(yp0 * PW + xp0) | ((unsigned int)(xp1 - xp0) << 13) |
                      ((unsigned int)(yp1 - yp0) << 14);
    float w00 = (1.f - fy) * (1.f - fx) * mv;
    float w01 = (1.f - fy) * fx * mv;
    float w10 = fy * (1.f - fx) * mv;
    float w11 = fy * fx * mv;
    u32x4 o;
    o[0] = iv;
    o[1] = pkbf(w00, w01);
    o[2] = pkbf(w10, w11);
    o[3] = 0;
    *((u32x4*)om + idx) = o;
}

// ======================================================================
// GEMM geometry: block = 512 thr = 8 waves. Tile M=256 oc, N=32 px, K-step 64
// (two 32-chunks per barrier). Grid: (256 rows, 2 px-halves) = 512 blocks.
// A: 32KB/iter via global_load_lds (pack pre-swizzled, LDS linear, swizzled read).
// B: sampled 8B/thread, XOR-swizzled writes. All LDS accesses 2-way max (free).
// ======================================================================

// A stage: wave wu stages 4KB of the 32KB pair-tile (T even)
#define A_STAGE2(WPP, T, BUF)                                                         \
    {                                                                                 \
        const unsigned short* s1_ = WPP + (size_t)(T) * 8192 + wu * 2048 + lane * 8;  \
        glds16(s1_, &sA[BUF][wu * 2048]);                                             \
        glds16(s1_ + 512, &sA[BUF][wu * 2048 + 512]);                                 \
        glds16(s1_ + 1024, &sA[BUF][wu * 2048 + 1024]);                               \
        glds16(s1_ + 1536, &sA[BUF][wu * 2048 + 1536]);                               \
    }

// 8 MFMA: wave tile 32oc x 32px, K=64
#define MFMA8(BUF)                                                                           \
    {                                                                                        \
        int sw_ = (lg ^ ((r16 >> 1) & 3)) << 3;                                              \
        _Pragma("unroll") for (int kt = 0; kt < 2; kt++) {                                   \
            s16x8 a0 = *(const s16x8*)&sA[BUF][kt * 8192 + (w * 32 + r16) * 32 + sw_];       \
            s16x8 a1 = *(const s16x8*)&sA[BUF][kt * 8192 + (w * 32 + 16 + r16) * 32 + sw_];  \
            s16x8 b0 = *(const s16x8*)&sB[BUF][kt][r16 * 32 + sw_];                          \
            s16x8 b1 = *(const s16x8*)&sB[BUF][kt][(16 + r16) * 32 + sw_];                   \
            acc[0][0] = __builtin_amdgcn_mfma_f32_16x16x32_bf16(a0, b0, acc[0][0], 0, 0, 0); \
            acc[0][1] = __builtin_amdgcn_mfma_f32_16x16x32_bf16(a0, b1, acc[0][1], 0, 0, 0); \
            acc[1][0] = __builtin_amdgcn_mfma_f32_16x16x32_bf16(a1, b0, acc[1][0], 0, 0, 0); \
            acc[1][1] = __builtin_amdgcn_mfma_f32_16x16x32_bf16(a1, b1, acc[1][1], 0, 0, 0); \
        }                                                                                    \
    }

// B write slot (elements) for thread (px_l, ch2): matches read swizzle, 2-way free
#define BSLOT (px_l * 32 + ((((ch2 >> 2) ^ ((px_l >> 1) & 3))) << 3) + (ch2 & 3) * 2)

// ======================================================================
// offset conv
// ======================================================================
__global__ __launch_bounds__(512, 4) void off_mfma(const unsigned short* __restrict__ eT,
                                                   const unsigned short* __restrict__ wp,
                                                   const float* __restrict__ off_b,
                                                   float* __restrict__ om4) {
    __shared__ __align__(16) unsigned short sA[2][16384];
    __shared__ __align__(16) unsigned short sB[2][2][1024];
    int bx = blockIdx.x;
    int b = bx >> 6, y = bx & 63;
    int pxh = blockIdx.y;
    int tid = threadIdx.x;
    int lane = tid & 63;
    int w = tid >> 6;
    int wu = __builtin_amdgcn_readfirstlane(w);
    int r16 = lane & 15, lg = lane >> 4;
    int px_l = tid >> 4, ch2 = tid & 15;
    int pxg = pxh * 32 + px_l;

    const unsigned short* eb = eT + (size_t)b * PH * PW * CC;

    f32x4 acc[2][2];
#pragma unroll
    for (int mi = 0; mi < 2; mi++)
#pragma unroll
        for (int ni = 0; ni < 2; ni++) acc[mi][ni] = (f32x4)0.f;

#define OF_B(T, BV)                                                                          \
    {                                                                                        \
        int tap_ = (T) >> 3, cg_ = (T) & 7;                                                  \
        int ky_ = tap_ / 3, kx_ = tap_ - ky_ * 3;                                            \
        BV = *(const unsigned int*)&eb[(size_t)((y + ky_ + 1) * PW + (pxg + kx_ + 1)) * CC + \
                                       cg_ * 32 + ch2 * 2];                                  \
    }
#define OF_IT2(T, BUF)                                                       \
    {                                                                        \
        __syncthreads();                                                     \
        unsigned int bv0_ = 0, bv1_ = 0;                                     \
        if ((T) + 2 < NCHUNK) {                                              \
            A_STAGE2(wp, (T) + 2, (BUF) ^ 1)                                 \
            OF_B((T) + 2, bv0_)                                              \
            OF_B((T) + 3, bv1_)                                              \
        }                                                                    \
        MFMA8(BUF)                                                           \
        if ((T) + 2 < NCHUNK) {                                              \
            *(unsigned int*)&sB[(BUF) ^ 1][0][BSLOT] = bv0_;                 \
            *(unsigned int*)&sB[(BUF) ^ 1][1][BSLOT] = bv1_;                 \
        }                                                                    \
    }

    {
        A_STAGE2(wp, 0, 0)
        unsigned int b0v, b1v;
        OF_B(0, b0v)
        OF_B(1, b1v)
        *(unsigned int*)&sB[0][0][BSLOT] = b0v;
        *(unsigned int*)&sB[0][1][BSLOT] = b1v;
    }
    for (int t = 0; t < NCHUNK; t += 4) {
        OF_IT2(t, 0)
        OF_IT2(t + 2, 1)
    }

    float* omb4 = om4 + (size_t)b * NCHUNK * HW * 4;
#pragma unroll
    for (int mi = 0; mi < 2; mi++) {
#pragma unroll
        for (int ni = 0; ni < 2; ni++) {
#pragma unroll
            for (int j = 0; j < 4; j++) {
                int oc = w * 32 + mi * 16 + lg * 4 + j;
                if (oc < OFFC) {
                    int pxo = pxh * 32 + ni * 16 + r16;
                    float v = acc[mi][ni][j] + off_b[oc];
                    int dg, tap, comp;
                    if (oc < 144) {
                        dg = oc / 18;
                        int rr = oc - dg * 18;
                        tap = rr >> 1;
                        comp = rr & 1;
                    } else {
                        int o2 = oc - 144;
                        dg = o2 / 9;
                        tap = o2 - dg * 9;
                        comp = 2;
                    }
                    omb4[((size_t)(dg * 9 + tap) * HW + y * WW + pxo) * 4 + comp] = v;
                }
            }
        }
    }
}

// ======================================================================
// fused deformable sampling + main conv
// ======================================================================
__global__ __launch_bounds__(512, 4) void dconv_mfma(const unsigned short* __restrict__ xT,
                                                     const float* __restrict__ omP,
                                                     const unsigned short* __restrict__ wp,
                                                     const float* __restrict__ bias,
                                                     float* __restrict__ out) {
    __shared__ __align__(16) unsigned short sA[2][16384];
    __shared__ __align__(16) unsigned short sB[2][2][1024];
    int bx = blockIdx.x;
    int b = bx >> 6, y = bx & 63;
    int pxh = blockIdx.y;
    int tid = threadIdx.x;
    int lane = tid & 63;
    int w = tid >> 6;
    int wu = __builtin_amdgcn_readfirstlane(w);
    int r16 = lane & 15, lg = lane >> 4;
    int px_l = tid >> 4, ch2 = tid & 15;
    int yx = y * WW + pxh * 32 + px_l;

    const unsigned short* xb = xT + (size_t)b * PH * PW * CC;
    const float* omPb = omP + (size_t)b * NCHUNK * HW * 4;

    f32x4 acc[2][2];
#pragma unroll
    for (int mi = 0; mi < 2; mi++)
#pragma unroll
        for (int ni = 0; ni < 2; ni++) acc[mi][ni] = (f32x4)0.f;

#define DC_OML(T) (*(const u32x4*)(omPb + ((size_t)(T)*HW + yx) * 4))

#define DC_G(T, OM, G00, G01, G10, G11)                                   \
    {                                                                     \
        int dg_ = ((T) * 57) >> 9;                                        \
        unsigned int iv_ = OM[0];                                         \
        int o00_ = (int)(iv_ & 8191u) << 8;                               \
        int dxe_ = (int)((iv_ >> 13) & 1u) << 8;                          \
        int dye_ = ((iv_ >> 14) & 1u) ? (PW * CC) : 0;                    \
        const unsigned short* p_ = xb + dg_ * 32 + ch2 * 2;               \
        G00 = *(const unsigned int*)(p_ + o00_);                          \
        G01 = *(const unsigned int*)(p_ + o00_ + dxe_);                   \
        G10 = *(const unsigned int*)(p_ + o00_ + dye_);                   \
        G11 = *(const unsigned int*)(p_ + o00_ + dye_ + dxe_);            \
    }
#define DC_FIN(OM, G00, G01, G10, G11, BUF, KT)                                           \
    {                                                                                     \
        float w00 = bflo(OM[1]), w01 = bfhi(OM[1]);                                       \
        float w10 = bflo(OM[2]), w11 = bfhi(OM[2]);                                       \
        float v0 = w00 * bflo(G00) + w01 * bflo(G01) + w10 * bflo(G10) + w11 * bflo(G11); \
        float v1 = w00 * bfhi(G00) + w01 * bfhi(G01) + w10 * bfhi(G10) + w11 * bfhi(G11); \
        *(unsigned int*)&sB[BUF][KT][BSLOT] = pkbf(v0, v1);                               \
    }
#define DC_IT2(T, BUF, OMC0, OMC1, OMN0, OMN1)                               \
    {                                                                        \
        __syncthreads();                                                     \
        unsigned int g00, g01, g02, g03, g10, g11, g12, g13;                 \
        if ((T) + 2 < NCHUNK) {                                              \
            A_STAGE2(wp, (T) + 2, (BUF) ^ 1)                                 \
            DC_G((T) + 2, OMC0, g00, g01, g02, g03)                          \
            DC_G((T) + 3, OMC1, g10, g11, g12, g13)                          \
        }                                                                    \
        if ((T) + 4 < NCHUNK) {                                              \
            OMN0 = DC_OML((T) + 4);                                          \
            OMN1 = DC_OML((T) + 5);                                          \
        }                                                                    \
        MFMA8(BUF)                                                           \
        if ((T) + 2 < NCHUNK) {                                              \
            DC_FIN(OMC0, g00, g01, g02, g03, (BUF) ^ 1, 0)                   \
            DC_FIN(OMC1, g10, g11, g12, g13, (BUF) ^ 1, 1)                   \
        }                                                                    \
    }

    u32x4 omC0, omC1, omN0, omN1;
    {
        A_STAGE2(wp, 0, 0)
        u32x4 om0 = DC_OML(0);
        u32x4 om1 = DC_OML(1);
        unsigned int g00, g01, g02, g03, g10, g11, g12, g13;
        DC_G(0, om0, g00, g01, g02, g03)
        DC_G(1, om1, g10, g11, g12, g13)
        omC0 = DC_OML(2);
        omC1 = DC_OML(3);
        DC_FIN(om0, g00, g01, g02, g03, 0, 0)
        DC_FIN(om1, g10, g11, g12, g13, 0, 1)
    }
    for (int t = 0; t < NCHUNK; t += 8) {
        DC_IT2(t, 0, omC0, omC1, omN0, omN1)
        DC_IT2(t + 2, 1, omN0, omN1, omC0, omC1)
        DC_IT2(t + 4, 0, omC0, omC1, omN0, omN1)
        DC_IT2(t + 6, 1, omN0, omN1, omC0, omC1)
    }

#pragma unroll
    for (int mi = 0; mi < 2; mi++) {
#pragma unroll
        for (int ni = 0; ni < 2; ni++) {
#pragma unroll
            for (int j = 0; j < 4; j++) {
                int oc = w * 32 + mi * 16 + lg * 4 + j;
                int pxo = pxh * 32 + ni * 16 + r16;
                out[(size_t)(b * COUT + oc) * HW + y * WW + pxo] = acc[mi][ni][j] + bias[oc];
            }
        }
    }
}

extern "C" void kernel_launch(void* const* d_in, const int* in_sizes, int n_in,
                              void* d_out, int out_size, void* d_ws, size_t ws_size,
                              hipStream_t stream) {
    const float* x = (const float*)d_in[0];
    const float* extra_feat = (const float*)d_in[1];
    const float* weight = (const float*)d_in[2];
    const float* bias = (const float*)d_in[3];
    const float* off_w = (const float*)d_in[4];
    const float* off_b = (const float*)d_in[5];
    float* out = (float*)d_out;

    float* omP = (float*)d_ws;
    unsigned short* wpm = (unsigned short*)(omP + (size_t)BB * NCHUNK * HW * 4);
    unsigned short* wpo = wpm + (size_t)KTOT * COUT;
    unsigned short* xT = wpo + (size_t)KTOT * COUT;
    unsigned short* eT = xT + (size_t)BB * PH * PW * CC;

    pack_w_main<<<(KTOT * COUT) / 256, 256, 0, stream>>>(weight, wpm);
    pack_w_off<<<(KTOT * COUT) / 256, 256, 0, stream>>>(off_w, wpo);
    pad_tr2<<<dim3(BB * PH, 2), 256, 0, stream>>>(x, extra_feat, xT, eT);

    off_mfma<<<dim3(BB * HH, 2), 512, 0, stream>>>(eT, wpo, off_b, omP);
    prep_off<<<(BB * NCHUNK * HW) / 256, 256, 0, stream>>>(omP);
    dconv_mfma<<<dim3(BB * HH, 2), 512, 0, stream>>>(xT, omP, wpm, bias, out);
}

// Round 10
// 122.379 us; speedup vs baseline: 1.2925x; 1.0778x over previous
//
#include <hip/hip_runtime.h>
#include <hip/hip_bf16.h>
#include <math.h>

#define BB 4
#define CC 256
#define HH 64
#define WW 64
#define HW 4096
#define PH 68
#define PW 68
#define COUT 256
#define OFFC 216
#define KTOT 2304
#define NCHUNK 72

typedef __attribute__((ext_vector_type(4))) float f32x4;
typedef __attribute__((ext_vector_type(8))) short s16x8;
typedef __attribute__((ext_vector_type(8))) unsigned short u16x8;
typedef __attribute__((ext_vector_type(2))) unsigned int u32x2;
typedef __attribute__((ext_vector_type(4))) unsigned int u32x4;

__device__ __forceinline__ unsigned short f2bf(float f) {
    unsigned int u = __float_as_uint(f);
    return (unsigned short)((u + 0x7fffu + ((u >> 16) & 1u)) >> 16);
}
__device__ __forceinline__ float bflo(unsigned int u) { return __uint_as_float(u << 16); }
__device__ __forceinline__ float bfhi(unsigned int u) { return __uint_as_float(u & 0xffff0000u); }
__device__ __forceinline__ unsigned int pkbf(float a, float b) {
    __hip_bfloat162 h = __float22bfloat162_rn(make_float2(a, b));
    unsigned int r;
    __builtin_memcpy(&r, &h, 4);
    return r;
}
__device__ __forceinline__ void glds16(const void* g, void* l) {
    __builtin_amdgcn_global_load_lds((const __attribute__((address_space(1))) unsigned int*)g,
                                     (__attribute__((address_space(3))) unsigned int*)l, 16, 0, 0);
}

// ---------- pack main weight, k-swizzled per oc row (2-row granular):
// wp[t][oc][s*8+e] = w[oc][c = dg*32 + ((s^((oc>>1)&3))*8+e)][tap],  t = dg*9+tap
__global__ __launch_bounds__(256) void pack_w_main(const float* __restrict__ w,
                                                   unsigned short* __restrict__ wp) {
    int idx = blockIdx.x * 256 + threadIdx.x;
    int t = idx >> 13, r = idx & 8191;
    int oc = r >> 5, s = (r >> 3) & 3, e = r & 7;
    int kk = ((s ^ ((oc >> 1) & 3)) << 3) | e;
    int dg = t / 9, tap = t - dg * 9;
    int c = dg * 32 + kk;
    wp[idx] = f2bf(w[((size_t)oc * CC + c) * 9 + tap]);
}

// ---------- pack offset weight (pad 216->256), t = tap*8+cg, same swizzle
__global__ __launch_bounds__(256) void pack_w_off(const float* __restrict__ w,
                                                  unsigned short* __restrict__ wp) {
    int idx = blockIdx.x * 256 + threadIdx.x;
    int t = idx >> 13, r = idx & 8191;
    int oc = r >> 5, s = (r >> 3) & 3, e = r & 7;
    int kk = ((s ^ ((oc >> 1) & 3)) << 3) | e;
    int tap = t >> 3, cg = t & 7;
    int c = cg * 32 + kk;
    float v = (oc < OFFC) ? w[((size_t)oc * CC + c) * 9 + tap] : 0.f;
    wp[idx] = f2bf(v);
}

// ---------- NCHW f32 -> padded NHWC bf16 (zero ring of 2), LDS-transposed coalesced
__global__ __launch_bounds__(256) void pad_tr2(const float* __restrict__ srcx,
                                               const float* __restrict__ srce,
                                               unsigned short* __restrict__ dx_,
                                               unsigned short* __restrict__ de_) {
    const float* src = blockIdx.y ? srce : srcx;
    unsigned short* dst = blockIdx.y ? de_ : dx_;
    int blk = blockIdx.x;
    int b = blk / PH, yp = blk % PH;
    int y = yp - 2;
    unsigned short* drow = dst + ((size_t)b * PH + yp) * PW * CC;
    int tid = threadIdx.x;
    if ((unsigned)y >= (unsigned)HH) {
        for (int i = tid; i < PW * CC / 8; i += 256) *(u16x8*)&drow[(size_t)i * 8] = (u16x8)0;
        return;
    }
    __shared__ float tile[64][65];
    int lane = tid & 63, w = tid >> 6;
    int oct = tid & 7, xi = tid >> 3;
    const float* srow = src + (size_t)b * CC * HW + (size_t)y * WW;
    for (int chunk = 0; chunk < 4; chunk++) {
        __syncthreads();
#pragma unroll
        for (int i = 0; i < 16; i++) {
            int c = chunk * 64 + w * 16 + i;
            tile[w * 16 + i][lane] = srow[(size_t)c * HW + lane];
        }
        __syncthreads();
#pragma unroll
        for (int xq = 0; xq < 3; xq++) {
            int xp = xq * 32 + xi;
            if (xp < PW) {
                int x = xp - 2;
                u16x8 v = (u16x8)0;
                if ((unsigned)x < (unsigned)WW) {
#pragma unroll
                    for (int e = 0; e < 8; e++) v[e] = f2bf(tile[oct * 8 + e][x]);
                }
                *(u16x8*)&drow[(size_t)xp * CC + chunk * 64 + oct * 8] = v;
            }
        }
    }
}

// ======================================================================
// GEMM geometry: block = 512 thr = 8 waves. Tile M=256 oc, N=32 px, K-step 64.
// Grid: (256 rows, 2 px-halves). A via global_load_lds (pre-swizzled pack,
// linear LDS dest, swizzled b128 read). All LDS access <=2-way (verified R9: 0 conflicts).
// ======================================================================

#define A_STAGE2(WPP, T, BUF)                                                         \
    {                                                                                 \
        const unsigned short* s1_ = WPP + (size_t)(T) * 8192 + wu * 2048 + lane * 8;  \
        glds16(s1_, &sA[BUF][wu * 2048]);                                             \
        glds16(s1_ + 512, &sA[BUF][wu * 2048 + 512]);                                 \
        glds16(s1_ + 1024, &sA[BUF][wu * 2048 + 1024]);                               \
        glds16(s1_ + 1536, &sA[BUF][wu * 2048 + 1536]);                               \
    }

#define MFMA8(BUF)                                                                           \
    {                                                                                        \
        int sw_ = (lg ^ ((r16 >> 1) & 3)) << 3;                                              \
        _Pragma("unroll") for (int kti = 0; kti < 2; kti++) {                                \
            s16x8 a0 = *(const s16x8*)&sA[BUF][kti * 8192 + (w * 32 + r16) * 32 + sw_];      \
            s16x8 a1 = *(const s16x8*)&sA[BUF][kti * 8192 + (w * 32 + 16 + r16) * 32 + sw_]; \
            s16x8 b0 = *(const s16x8*)&sB[BUF][kti][r16 * 32 + sw_];                         \
            s16x8 b1 = *(const s16x8*)&sB[BUF][kti][(16 + r16) * 32 + sw_];                  \
            acc[0][0] = __builtin_amdgcn_mfma_f32_16x16x32_bf16(a0, b0, acc[0][0], 0, 0, 0); \
            acc[0][1] = __builtin_amdgcn_mfma_f32_16x16x32_bf16(a0, b1, acc[0][1], 0, 0, 0); \
            acc[1][0] = __builtin_amdgcn_mfma_f32_16x16x32_bf16(a1, b0, acc[1][0], 0, 0, 0); \
            acc[1][1] = __builtin_amdgcn_mfma_f32_16x16x32_bf16(a1, b1, acc[1][1], 0, 0, 0); \
        }                                                                                    \
    }

// ======================================================================
// offset conv + fused prep epilogue
// ======================================================================
__global__ __launch_bounds__(512, 4) void off_mfma(const unsigned short* __restrict__ eT,
                                                   const unsigned short* __restrict__ wp,
                                                   const float* __restrict__ off_b,
                                                   float* __restrict__ omP) {
    __shared__ __align__(16) unsigned short sA[2][16384];
    __shared__ __align__(16) unsigned short sB[2][2][1024];
    int bx = blockIdx.x;
    int b = bx >> 6, y = bx & 63;
    int pxh = blockIdx.y;
    int tid = threadIdx.x;
    int lane = tid & 63;
    int w = tid >> 6;
    int wu = __builtin_amdgcn_readfirstlane(w);
    int r16 = lane & 15, lg = lane >> 4;
    int px_l = tid >> 4, ch2 = tid & 15;
    int pxg = pxh * 32 + px_l;

    const unsigned short* eb = eT + (size_t)b * PH * PW * CC;

    f32x4 acc[2][2];
#pragma unroll
    for (int mi = 0; mi < 2; mi++)
#pragma unroll
        for (int ni = 0; ni < 2; ni++) acc[mi][ni] = (f32x4)0.f;

#define BSLOT2 (px_l * 32 + ((((ch2 >> 2) ^ ((px_l >> 1) & 3))) << 3) + (ch2 & 3) * 2)
#define OF_B(T, BV)                                                                          \
    {                                                                                        \
        int tap_ = (T) >> 3, cg_ = (T) & 7;                                                  \
        int ky_ = tap_ / 3, kx_ = tap_ - ky_ * 3;                                            \
        BV = *(const unsigned int*)&eb[(size_t)((y + ky_ + 1) * PW + (pxg + kx_ + 1)) * CC + \
                                       cg_ * 32 + ch2 * 2];                                  \
    }
#define OF_IT2(T, BUF)                                                       \
    {                                                                        \
        __syncthreads();                                                     \
        unsigned int bv0_ = 0, bv1_ = 0;                                     \
        if ((T) + 2 < NCHUNK) {                                              \
            A_STAGE2(wp, (T) + 2, (BUF) ^ 1)                                 \
            OF_B((T) + 2, bv0_)                                              \
            OF_B((T) + 3, bv1_)                                              \
        }                                                                    \
        MFMA8(BUF)                                                           \
        if ((T) + 2 < NCHUNK) {                                              \
            *(unsigned int*)&sB[(BUF) ^ 1][0][BSLOT2] = bv0_;                \
            *(unsigned int*)&sB[(BUF) ^ 1][1][BSLOT2] = bv1_;                \
        }                                                                    \
    }

    {
        A_STAGE2(wp, 0, 0)
        unsigned int b0v, b1v;
        OF_B(0, b0v)
        OF_B(1, b1v)
        *(unsigned int*)&sB[0][0][BSLOT2] = b0v;
        *(unsigned int*)&sB[0][1][BSLOT2] = b1v;
    }
    for (int t = 0; t < NCHUNK; t += 4) {
        OF_IT2(t, 0)
        OF_IT2(t + 2, 1)
    }

    // ---------- fused prep epilogue ----------
    __syncthreads();
    float* sAcc = (float*)sA;   // 256 x 33 f32 = 33 KB, reuses sA
#pragma unroll
    for (int mi = 0; mi < 2; mi++) {
#pragma unroll
        for (int ni = 0; ni < 2; ni++) {
#pragma unroll
            for (int j = 0; j < 4; j++) {
                int oc = w * 32 + mi * 16 + lg * 4 + j;
                float bv = (oc < OFFC) ? off_b[oc] : 0.f;
                sAcc[oc * 33 + ni * 16 + r16] = acc[mi][ni][j] + bv;
            }
        }
    }
    __syncthreads();
    float* omPb = omP + (size_t)b * NCHUNK * HW * 4;
    for (int i = tid; i < NCHUNK * 32; i += 512) {
        int tt = i >> 5, px = i & 31;
        int dg = (tt * 57) >> 9;
        int tap = tt - dg * 9;
        int ky = tap / 3, kx = tap - ky * 3;
        float dyv = sAcc[(dg * 18 + 2 * tap) * 33 + px];
        float dxv = sAcc[(dg * 18 + 2 * tap + 1) * 33 + px];
        float mr = sAcc[(144 + dg * 9 + tap) * 33 + px];
        int xg = pxh * 32 + px;
        float mv = 1.f / (1.f + __expf(-mr));
        float py = (float)(y + ky - 1) + dyv;
        float pxx = (float)(xg + kx - 1) + dxv;
        float y0f = floorf(py), x0f = floorf(pxx);
        float fy = py - y0f, fx = pxx - x0f;
        int yp0 = min(max((int)y0f + 2, 0), PH - 1);
        int yp1 = min(max((int)y0f + 3, 0), PH - 1);
        int xp0 = min(max((int)x0f + 2, 0), PW - 1);
        int xp1 = min(max((int)x0f + 3, 0), PW - 1);
        unsigned int iv = (unsigned int)(yp0 * PW + xp0) | ((unsigned int)(xp1 - xp0) << 13) |
                          ((unsigned int)(yp1 - yp0) << 14);
        float w00 = (1.f - fy) * (1.f - fx) * mv;
        float w01 = (1.f - fy) * fx * mv;
        float w10 = fy * (1.f - fx) * mv;
        float w11 = fy * fx * mv;
        u32x4 o;
        o[0] = iv;
        o[1] = pkbf(w00, w01);
        o[2] = pkbf(w10, w11);
        o[3] = 0;
        *(u32x4*)(omPb + ((size_t)tt * HW + y * WW + xg) * 4) = o;
    }
}

// ======================================================================
// fused deformable sampling + main conv.
// Sampling threads: kt = tid>>8 (K32 chunk), px_l = (tid>>3)&31, ch4 = tid&7 (4 ch, 8B).
// ======================================================================
__global__ __launch_bounds__(512, 4) void dconv_mfma(const unsigned short* __restrict__ xT,
                                                     const float* __restrict__ omP,
                                                     const unsigned short* __restrict__ wp,
                                                     const float* __restrict__ bias,
                                                     float* __restrict__ out) {
    __shared__ __align__(16) unsigned short sA[2][16384];
    __shared__ __align__(16) unsigned short sB[2][2][1024];
    int bx = blockIdx.x;
    int b = bx >> 6, y = bx & 63;
    int pxh = blockIdx.y;
    int tid = threadIdx.x;
    int lane = tid & 63;
    int w = tid >> 6;
    int wu = __builtin_amdgcn_readfirstlane(w);
    int r16 = lane & 15, lg = lane >> 4;
    int kt = tid >> 8;              // wave-uniform: waves 0-3 -> kt0, 4-7 -> kt1
    int px_l = (tid >> 3) & 31;
    int ch4 = tid & 7;
    int yx = y * WW + pxh * 32 + px_l;

    const unsigned short* xb = xT + (size_t)b * PH * PW * CC;
    const float* omPb = omP + (size_t)b * NCHUNK * HW * 4;

    f32x4 acc[2][2];
#pragma unroll
    for (int mi = 0; mi < 2; mi++)
#pragma unroll
        for (int ni = 0; ni < 2; ni++) acc[mi][ni] = (f32x4)0.f;

#define BSLOT4 (px_l * 32 + ((((ch4 >> 1) ^ ((px_l >> 1) & 3))) << 3) + (ch4 & 1) * 4)
#define DC_OML(T) (*(const u32x4*)(omPb + ((size_t)(T)*HW + yx) * 4))

    // gather 4 corners x 4 channels (8B each) for chunk T (T includes kt)
#define DC_G(T, OM, G00, G01, G10, G11)                                   \
    {                                                                     \
        int dg_ = ((T) * 57) >> 9;                                        \
        unsigned int iv_ = OM[0];                                         \
        int o00_ = (int)(iv_ & 8191u) << 8;                               \
        int dxe_ = (int)((iv_ >> 13) & 1u) << 8;                          \
        int dye_ = ((iv_ >> 14) & 1u) ? (PW * CC) : 0;                    \
        const unsigned short* p_ = xb + dg_ * 32 + ch4 * 4;               \
        G00 = *(const u32x2*)(p_ + o00_);                                 \
        G01 = *(const u32x2*)(p_ + o00_ + dxe_);                          \
        G10 = *(const u32x2*)(p_ + o00_ + dye_);                          \
        G11 = *(const u32x2*)(p_ + o00_ + dye_ + dxe_);                   \
    }
#define DC_FIN(OM, G00, G01, G10, G11, BUF)                                               \
    {                                                                                     \
        float w00 = bflo(OM[1]), w01 = bfhi(OM[1]);                                       \
        float w10 = bflo(OM[2]), w11 = bfhi(OM[2]);                                       \
        float v0 = w00 * bflo(G00[0]) + w01 * bflo(G01[0]) + w10 * bflo(G10[0]) +         \
                   w11 * bflo(G11[0]);                                                    \
        float v1 = w00 * bfhi(G00[0]) + w01 * bfhi(G01[0]) + w10 * bfhi(G10[0]) +         \
                   w11 * bfhi(G11[0]);                                                    \
        float v2 = w00 * bflo(G00[1]) + w01 * bflo(G01[1]) + w10 * bflo(G10[1]) +         \
                   w11 * bflo(G11[1]);                                                    \
        float v3 = w00 * bfhi(G00[1]) + w01 * bfhi(G01[1]) + w10 * bfhi(G10[1]) +         \
                   w11 * bfhi(G11[1]);                                                    \
        u32x2 pk_;                                                                        \
        pk_[0] = pkbf(v0, v1);                                                            \
        pk_[1] = pkbf(v2, v3);                                                            \
        *(u32x2*)&sB[BUF][kt][BSLOT4] = pk_;                                              \
    }
#define DC_IT2(T, BUF, OMC, OMN)                                             \
    {                                                                        \
        __syncthreads();                                                     \
        u32x2 g00, g01, g10, g11;                                            \
        if ((T) + 2 < NCHUNK) {                                              \
            A_STAGE2(wp, (T) + 2, (BUF) ^ 1)                                 \
            DC_G((T) + 2 + kt, OMC, g00, g01, g10, g11)                      \
        }                                                                    \
        if ((T) + 4 < NCHUNK) OMN = DC_OML((T) + 4 + kt);                    \
        MFMA8(BUF)                                                           \
        if ((T) + 2 < NCHUNK) DC_FIN(OMC, g00, g01, g10, g11, (BUF) ^ 1)     \
    }

    u32x4 omC, omN;
    {
        A_STAGE2(wp, 0, 0)
        u32x4 om0 = DC_OML(kt);
        u32x2 g00, g01, g10, g11;
        DC_G(kt, om0, g00, g01, g10, g11)
        omC = DC_OML(2 + kt);
        DC_FIN(om0, g00, g01, g10, g11, 0)
    }
    for (int t = 0; t < NCHUNK; t += 4) {
        DC_IT2(t, 0, omC, omN)
        DC_IT2(t + 2, 1, omN, omC)
    }

#pragma unroll
    for (int mi = 0; mi < 2; mi++) {
#pragma unroll
        for (int ni = 0; ni < 2; ni++) {
#pragma unroll
            for (int j = 0; j < 4; j++) {
                int oc = w * 32 + mi * 16 + lg * 4 + j;
                int pxo = pxh * 32 + ni * 16 + r16;
                out[(size_t)(b * COUT + oc) * HW + y * WW + pxo] = acc[mi][ni][j] + bias[oc];
            }
        }
    }
}

extern "C" void kernel_launch(void* const* d_in, const int* in_sizes, int n_in,
                              void* d_out, int out_size, void* d_ws, size_t ws_size,
                              hipStream_t stream) {
    const float* x = (const float*)d_in[0];
    const float* extra_feat = (const float*)d_in[1];
    const float* weight = (const float*)d_in[2];
    const float* bias = (const float*)d_in[3];
    const float* off_w = (const float*)d_in[4];
    const float* off_b = (const float*)d_in[5];
    float* out = (float*)d_out;

    float* omP = (float*)d_ws;
    unsigned short* wpm = (unsigned short*)(omP + (size_t)BB * NCHUNK * HW * 4);
    unsigned short* wpo = wpm + (size_t)KTOT * COUT;
    unsigned short* xT = wpo + (size_t)KTOT * COUT;
    unsigned short* eT = xT + (size_t)BB * PH * PW * CC;

    pack_w_main<<<(KTOT * COUT) / 256, 256, 0, stream>>>(weight, wpm);
    pack_w_off<<<(KTOT * COUT) / 256, 256, 0, stream>>>(off_w, wpo);
    pad_tr2<<<dim3(BB * PH, 2), 256, 0, stream>>>(x, extra_feat, xT, eT);

    off_mfma<<<dim3(BB * HH, 2), 512, 0, stream>>>(eT, wpo, off_b, omP);
    dconv_mfma<<<dim3(BB * HH, 2), 512, 0, stream>>>(xT, omP, wpm, bias, out);
}

// Round 11
// 117.540 us; speedup vs baseline: 1.3457x; 1.0412x over previous
//
#include <hip/hip_runtime.h>
#include <hip/hip_bf16.h>
#include <math.h>

#define BB 4
#define CC 256
#define HH 64
#define WW 64
#define HW 4096
#define PH 68
#define PW 68
#define COUT 256
#define OFFC 216
#define KTOT 2304
#define NCHUNK 72

typedef __attribute__((ext_vector_type(4))) float f32x4;
typedef __attribute__((ext_vector_type(8))) short s16x8;
typedef __attribute__((ext_vector_type(8))) unsigned short u16x8;
typedef __attribute__((ext_vector_type(2))) unsigned int u32x2;
typedef __attribute__((ext_vector_type(4))) unsigned int u32x4;

__device__ __forceinline__ unsigned short f2bf(float f) {
    unsigned int u = __float_as_uint(f);
    return (unsigned short)((u + 0x7fffu + ((u >> 16) & 1u)) >> 16);
}
__device__ __forceinline__ float bflo(unsigned int u) { return __uint_as_float(u << 16); }
__device__ __forceinline__ float bfhi(unsigned int u) { return __uint_as_float(u & 0xffff0000u); }
__device__ __forceinline__ unsigned int pkbf(float a, float b) {
    __hip_bfloat162 h = __float22bfloat162_rn(make_float2(a, b));
    unsigned int r;
    __builtin_memcpy(&r, &h, 4);
    return r;
}
__device__ __forceinline__ void glds16(const void* g, void* l) {
    __builtin_amdgcn_global_load_lds((const __attribute__((address_space(1))) unsigned int*)g,
                                     (__attribute__((address_space(3))) unsigned int*)l, 16, 0, 0);
}

// counted waits (m201 pattern): per-wave pre-drain + raw barrier; never full vmcnt drain in steady state
#define WAITV(N) asm volatile("s_waitcnt vmcnt(" #N ")" ::: "memory")
#define WAITL() asm volatile("s_waitcnt lgkmcnt(0)" ::: "memory")
#define RBAR() __builtin_amdgcn_s_barrier()

// ---------- pack main weight, k-swizzled per oc row (2-row granular)
__global__ __launch_bounds__(256) void pack_w_main(const float* __restrict__ w,
                                                   unsigned short* __restrict__ wp) {
    int idx = blockIdx.x * 256 + threadIdx.x;
    int t = idx >> 13, r = idx & 8191;
    int oc = r >> 5, s = (r >> 3) & 3, e = r & 7;
    int kk = ((s ^ ((oc >> 1) & 3)) << 3) | e;
    int dg = t / 9, tap = t - dg * 9;
    int c = dg * 32 + kk;
    wp[idx] = f2bf(w[((size_t)oc * CC + c) * 9 + tap]);
}

// ---------- pack offset weight (pad 216->256), t = tap*8+cg, same swizzle
__global__ __launch_bounds__(256) void pack_w_off(const float* __restrict__ w,
                                                  unsigned short* __restrict__ wp) {
    int idx = blockIdx.x * 256 + threadIdx.x;
    int t = idx >> 13, r = idx & 8191;
    int oc = r >> 5, s = (r >> 3) & 3, e = r & 7;
    int kk = ((s ^ ((oc >> 1) & 3)) << 3) | e;
    int tap = t >> 3, cg = t & 7;
    int c = cg * 32 + kk;
    float v = (oc < OFFC) ? w[((size_t)oc * CC + c) * 9 + tap] : 0.f;
    wp[idx] = f2bf(v);
}

// ---------- NCHW f32 -> padded NHWC bf16 (zero ring of 2), LDS-transposed coalesced
__global__ __launch_bounds__(256) void pad_tr2(const float* __restrict__ srcx,
                                               const float* __restrict__ srce,
                                               unsigned short* __restrict__ dx_,
                                               unsigned short* __restrict__ de_) {
    const float* src = blockIdx.y ? srce : srcx;
    unsigned short* dst = blockIdx.y ? de_ : dx_;
    int blk = blockIdx.x;
    int b = blk / PH, yp = blk % PH;
    int y = yp - 2;
    unsigned short* drow = dst + ((size_t)b * PH + yp) * PW * CC;
    int tid = threadIdx.x;
    if ((unsigned)y >= (unsigned)HH) {
        for (int i = tid; i < PW * CC / 8; i += 256) *(u16x8*)&drow[(size_t)i * 8] = (u16x8)0;
        return;
    }
    __shared__ float tile[64][65];
    int lane = tid & 63, w = tid >> 6;
    int oct = tid & 7, xi = tid >> 3;
    const float* srow = src + (size_t)b * CC * HW + (size_t)y * WW;
    for (int chunk = 0; chunk < 4; chunk++) {
        __syncthreads();
#pragma unroll
        for (int i = 0; i < 16; i++) {
            int c = chunk * 64 + w * 16 + i;
            tile[w * 16 + i][lane] = srow[(size_t)c * HW + lane];
        }
        __syncthreads();
#pragma unroll
        for (int xq = 0; xq < 3; xq++) {
            int xp = xq * 32 + xi;
            if (xp < PW) {
                int x = xp - 2;
                u16x8 v = (u16x8)0;
                if ((unsigned)x < (unsigned)WW) {
#pragma unroll
                    for (int e = 0; e < 8; e++) v[e] = f2bf(tile[oct * 8 + e][x]);
                }
                *(u16x8*)&drow[(size_t)xp * CC + chunk * 64 + oct * 8] = v;
            }
        }
    }
}

// ======================================================================
// GEMM geometry (unchanged from R10): block 512 thr = 8 waves, M=256 oc,
// N=32 px, K-step 64, grid (256 rows, 2 px-halves). Counted-vmcnt sync.
// ======================================================================

#define A_STAGE2(WPP, T, BUF)                                                         \
    {                                                                                 \
        const unsigned short* s1_ = WPP + (size_t)(T) * 8192 + wu * 2048 + lane * 8;  \
        glds16(s1_, &sA[BUF][wu * 2048]);                                             \
        glds16(s1_ + 512, &sA[BUF][wu * 2048 + 512]);                                 \
        glds16(s1_ + 1024, &sA[BUF][wu * 2048 + 1024]);                               \
        glds16(s1_ + 1536, &sA[BUF][wu * 2048 + 1536]);                               \
    }

#define MFMA8(BUF)                                                                           \
    {                                                                                        \
        int sw_ = (lg ^ ((r16 >> 1) & 3)) << 3;                                              \
        _Pragma("unroll") for (int kti = 0; kti < 2; kti++) {                                \
            s16x8 a0 = *(const s16x8*)&sA[BUF][kti * 8192 + (w * 32 + r16) * 32 + sw_];      \
            s16x8 a1 = *(const s16x8*)&sA[BUF][kti * 8192 + (w * 32 + 16 + r16) * 32 + sw_]; \
            s16x8 b0 = *(const s16x8*)&sB[BUF][kti][r16 * 32 + sw_];                         \
            s16x8 b1 = *(const s16x8*)&sB[BUF][kti][(16 + r16) * 32 + sw_];                  \
            acc[0][0] = __builtin_amdgcn_mfma_f32_16x16x32_bf16(a0, b0, acc[0][0], 0, 0, 0); \
            acc[0][1] = __builtin_amdgcn_mfma_f32_16x16x32_bf16(a0, b1, acc[0][1], 0, 0, 0); \
            acc[1][0] = __builtin_amdgcn_mfma_f32_16x16x32_bf16(a1, b0, acc[1][0], 0, 0, 0); \
            acc[1][1] = __builtin_amdgcn_mfma_f32_16x16x32_bf16(a1, b1, acc[1][1], 0, 0, 0); \
        }                                                                                    \
    }

// ======================================================================
// offset conv + fused prep epilogue (counted-vmcnt pipeline)
// ======================================================================
__global__ __launch_bounds__(512, 4) void off_mfma(const unsigned short* __restrict__ eT,
                                                   const unsigned short* __restrict__ wp,
                                                   const float* __restrict__ off_b,
                                                   float* __restrict__ omP) {
    __shared__ __align__(16) unsigned short sA[2][16384];
    __shared__ __align__(16) unsigned short sB[2][2][1024];
    int bx = blockIdx.x;
    int b = bx >> 6, y = bx & 63;
    int pxh = blockIdx.y;
    int tid = threadIdx.x;
    int lane = tid & 63;
    int w = tid >> 6;
    int wu = __builtin_amdgcn_readfirstlane(w);
    int r16 = lane & 15, lg = lane >> 4;
    int px_l = tid >> 4, ch2 = tid & 15;
    int pxg = pxh * 32 + px_l;

    const unsigned short* eb = eT + (size_t)b * PH * PW * CC;

    f32x4 acc[2][2];
#pragma unroll
    for (int mi = 0; mi < 2; mi++)
#pragma unroll
        for (int ni = 0; ni < 2; ni++) acc[mi][ni] = (f32x4)0.f;

#define BSLOT2 (px_l * 32 + ((((ch2 >> 2) ^ ((px_l >> 1) & 3))) << 3) + (ch2 & 3) * 2)
#define OF_B(T, BV)                                                                          \
    {                                                                                        \
        int tap_ = (T) >> 3, cg_ = (T) & 7;                                                  \
        int ky_ = tap_ / 3, kx_ = tap_ - ky_ * 3;                                            \
        BV = *(const unsigned int*)&eb[(size_t)((y + ky_ + 1) * PW + (pxg + kx_ + 1)) * CC + \
                                       cg_ * 32 + ch2 * 2];                                  \
    }
    // full steady iter: A(T+2) glds; load b(T+4,T+5); MFMA(T); vmcnt(6)->write b(T+2,T+3); vmcnt(2); bar
#define OF_ITF(T, BUF, BP0, BP1, BN0, BN1)                           \
    {                                                                \
        A_STAGE2(wp, (T) + 2, (BUF) ^ 1)                             \
        OF_B((T) + 4, BN0)                                           \
        OF_B((T) + 5, BN1)                                           \
        MFMA8(BUF)                                                   \
        WAITV(6);                                                    \
        *(unsigned int*)&sB[(BUF) ^ 1][0][BSLOT2] = BP0;             \
        *(unsigned int*)&sB[(BUF) ^ 1][1][BSLOT2] = BP1;             \
        WAITV(2);                                                    \
        WAITL();                                                     \
        RBAR();                                                      \
    }

    unsigned int bP0, bP1, bN0, bN1;
    {  // prologue
        A_STAGE2(wp, 0, 0)
        unsigned int c0, c1;
        OF_B(0, c0)
        OF_B(1, c1)
        WAITV(0);
        *(unsigned int*)&sB[0][0][BSLOT2] = c0;
        *(unsigned int*)&sB[0][1][BSLOT2] = c1;
        OF_B(2, bP0)
        OF_B(3, bP1)
        WAITL();
        RBAR();
    }
    for (int t = 0; t < 64; t += 4) {
        OF_ITF(t, 0, bP0, bP1, bN0, bN1)
        OF_ITF(t + 2, 1, bN0, bN1, bP0, bP1)
    }
    OF_ITF(64, 0, bP0, bP1, bN0, bN1)   // loads b(68,69)->bN
    OF_ITF(66, 1, bN0, bN1, bP0, bP1)   // loads b(70,71)->bP
    {  // T=68 safe tail
        A_STAGE2(wp, 70, 1)
        MFMA8(0)
        WAITV(0);
        *(unsigned int*)&sB[1][0][BSLOT2] = bP0;
        *(unsigned int*)&sB[1][1][BSLOT2] = bP1;
        WAITL();
        RBAR();
    }
    MFMA8(1)   // T=70

    // ---------- fused prep epilogue ----------
    __syncthreads();
    float* sAcc = (float*)sA;
#pragma unroll
    for (int mi = 0; mi < 2; mi++) {
#pragma unroll
        for (int ni = 0; ni < 2; ni++) {
#pragma unroll
            for (int j = 0; j < 4; j++) {
                int oc = w * 32 + mi * 16 + lg * 4 + j;
                float bv = (oc < OFFC) ? off_b[oc] : 0.f;
                sAcc[oc * 33 + ni * 16 + r16] = acc[mi][ni][j] + bv;
            }
        }
    }
    __syncthreads();
    float* omPb = omP + (size_t)b * NCHUNK * HW * 4;
    for (int i = tid; i < NCHUNK * 32; i += 512) {
        int tt = i >> 5, px = i & 31;
        int dg = (tt * 57) >> 9;
        int tap = tt - dg * 9;
        int ky = tap / 3, kx = tap - ky * 3;
        float dyv = sAcc[(dg * 18 + 2 * tap) * 33 + px];
        float dxv = sAcc[(dg * 18 + 2 * tap + 1) * 33 + px];
        float mr = sAcc[(144 + dg * 9 + tap) * 33 + px];
        int xg = pxh * 32 + px;
        float mv = 1.f / (1.f + __expf(-mr));
        float py = (float)(y + ky - 1) + dyv;
        float pxx = (float)(xg + kx - 1) + dxv;
        float y0f = floorf(py), x0f = floorf(pxx);
        float fy = py - y0f, fx = pxx - x0f;
        int yp0 = min(max((int)y0f + 2, 0), PH - 1);
        int yp1 = min(max((int)y0f + 3, 0), PH - 1);
        int xp0 = min(max((int)x0f + 2, 0), PW - 1);
        int xp1 = min(max((int)x0f + 3, 0), PW - 1);
        unsigned int iv = (unsigned int)(yp0 * PW + xp0) | ((unsigned int)(xp1 - xp0) << 13) |
                          ((unsigned int)(yp1 - yp0) << 14);
        float w00 = (1.f - fy) * (1.f - fx) * mv;
        float w01 = (1.f - fy) * fx * mv;
        float w10 = fy * (1.f - fx) * mv;
        float w11 = fy * fx * mv;
        u32x4 o;
        o[0] = iv;
        o[1] = pkbf(w00, w01);
        o[2] = pkbf(w10, w11);
        o[3] = 0;
        *(u32x4*)(omPb + ((size_t)tt * HW + y * WW + xg) * 4) = o;
    }
}

// ======================================================================
// fused deformable sampling + main conv (counted-vmcnt pipeline).
// Gathers issued one full barrier-iteration before FIN.
// ======================================================================
__global__ __launch_bounds__(512, 4) void dconv_mfma(const unsigned short* __restrict__ xT,
                                                     const float* __restrict__ omP,
                                                     const unsigned short* __restrict__ wp,
                                                     const float* __restrict__ bias,
                                                     float* __restrict__ out) {
    __shared__ __align__(16) unsigned short sA[2][16384];
    __shared__ __align__(16) unsigned short sB[2][2][1024];
    int bx = blockIdx.x;
    int b = bx >> 6, y = bx & 63;
    int pxh = blockIdx.y;
    int tid = threadIdx.x;
    int lane = tid & 63;
    int w = tid >> 6;
    int wu = __builtin_amdgcn_readfirstlane(w);
    int r16 = lane & 15, lg = lane >> 4;
    int kt = tid >> 8;
    int px_l = (tid >> 3) & 31;
    int ch4 = tid & 7;
    int yx = y * WW + pxh * 32 + px_l;

    const unsigned short* xb = xT + (size_t)b * PH * PW * CC;
    const float* omPb = omP + (size_t)b * NCHUNK * HW * 4;

    f32x4 acc[2][2];
#pragma unroll
    for (int mi = 0; mi < 2; mi++)
#pragma unroll
        for (int ni = 0; ni < 2; ni++) acc[mi][ni] = (f32x4)0.f;

#define BSLOT4 (px_l * 32 + ((((ch4 >> 1) ^ ((px_l >> 1) & 3))) << 3) + (ch4 & 1) * 4)
#define DC_OML(T) (*(const u32x4*)(omPb + ((size_t)(T)*HW + yx) * 4))

#define DC_G(T, OM, G00, G01, G10, G11)                                   \
    {                                                                     \
        int dg_ = ((T) * 57) >> 9;                                        \
        unsigned int iv_ = OM[0];                                         \
        int o00_ = (int)(iv_ & 8191u) << 8;                               \
        int dxe_ = (int)((iv_ >> 13) & 1u) << 8;                          \
        int dye_ = ((iv_ >> 14) & 1u) ? (PW * CC) : 0;                    \
        const unsigned short* p_ = xb + dg_ * 32 + ch4 * 4;               \
        G00 = *(const u32x2*)(p_ + o00_);                                 \
        G01 = *(const u32x2*)(p_ + o00_ + dxe_);                          \
        G10 = *(const u32x2*)(p_ + o00_ + dye_);                          \
        G11 = *(const u32x2*)(p_ + o00_ + dye_ + dxe_);                   \
    }
#define DC_FIN(OM, G00, G01, G10, G11, BUF)                                               \
    {                                                                                     \
        float w00 = bflo(OM[1]), w01 = bfhi(OM[1]);                                       \
        float w10 = bflo(OM[2]), w11 = bfhi(OM[2]);                                       \
        float v0 = w00 * bflo(G00[0]) + w01 * bflo(G01[0]) + w10 * bflo(G10[0]) +         \
                   w11 * bflo(G11[0]);                                                    \
        float v1 = w00 * bfhi(G00[0]) + w01 * bfhi(G01[0]) + w10 * bfhi(G10[0]) +         \
                   w11 * bfhi(G11[0]);                                                    \
        float v2 = w00 * bflo(G00[1]) + w01 * bflo(G01[1]) + w10 * bflo(G10[1]) +         \
                   w11 * bflo(G11[1]);                                                    \
        float v3 = w00 * bfhi(G00[1]) + w01 * bfhi(G01[1]) + w10 * bfhi(G10[1]) +         \
                   w11 * bfhi(G11[1]);                                                    \
        u32x2 pk_;                                                                        \
        pk_[0] = pkbf(v0, v1);                                                            \
        pk_[1] = pkbf(v2, v3);                                                            \
        *(u32x2*)&sB[BUF][kt][BSLOT4] = pk_;                                              \
    }

    // full steady iter at chunk-pair base T (even):
    // A(T+2); issue g(T+4); MFMA(T); vmcnt(9) [om1+A4+g4 newer] -> FIN(T+2);
    // load om(T+6) into SF; vmcnt(5) [g4+om1 stay]; lgkm; bar
#define DC_ITF(T, BUF, GP0, GP1, GP2, GP3, GN0, GN1, GN2, GN3, SF, SG)   \
    {                                                                    \
        A_STAGE2(wp, (T) + 2, (BUF) ^ 1)                                 \
        DC_G((T) + 4 + kt, SG, GN0, GN1, GN2, GN3)                       \
        MFMA8(BUF)                                                       \
        WAITV(9);                                                        \
        DC_FIN(SF, GP0, GP1, GP2, GP3, (BUF) ^ 1)                        \
        SF = DC_OML((T) + 6 + kt);                                       \
        WAITV(5);                                                        \
        WAITL();                                                         \
        RBAR();                                                          \
    }

    u32x4 omA, omB;
    u32x2 gA0, gA1, gA2, gA3, gB0, gB1, gB2, gB3;
    {  // prologue: sB[0]=pair0; gA=g(pair1); omA=om(pair1), omB=om(pair2) last (+1 count)
        A_STAGE2(wp, 0, 0)
        u32x4 om0 = DC_OML(kt);
        omA = DC_OML(2 + kt);
        u32x2 t0, t1, t2, t3;
        DC_G(kt, om0, t0, t1, t2, t3)
        WAITV(0);
        DC_FIN(om0, t0, t1, t2, t3, 0)
        DC_G(2 + kt, omA, gA0, gA1, gA2, gA3)
        omB = DC_OML(4 + kt);
        WAITL();
        RBAR();
    }
    for (int t = 0; t < 64; t += 4) {
        DC_ITF(t, 0, gA0, gA1, gA2, gA3, gB0, gB1, gB2, gB3, omA, omB)
        DC_ITF(t + 2, 1, gB0, gB1, gB2, gB3, gA0, gA1, gA2, gA3, omB, omA)
    }
    DC_ITF(64, 0, gA0, gA1, gA2, gA3, gB0, gB1, gB2, gB3, omA, omB)
    {  // T=66 safe: A(68); g(70)->gA using omA(=om70); MFMA(1); FIN(68) w/ omB(=om68), gB
        A_STAGE2(wp, 68, 0)
        DC_G(70 + kt, omA, gA0, gA1, gA2, gA3)
        MFMA8(1)
        WAITV(0);
        DC_FIN(omB, gB0, gB1, gB2, gB3, 0)
        WAITL();
        RBAR();
    }
    {  // T=68 safe: A(70); MFMA(0); FIN(70) w/ omA, gA
        A_STAGE2(wp, 70, 1)
        MFMA8(0)
        WAITV(0);
        DC_FIN(omA, gA0, gA1, gA2, gA3, 1)
        WAITL();
        RBAR();
    }
    MFMA8(1)   // T=70

#pragma unroll
    for (int mi = 0; mi < 2; mi++) {
#pragma unroll
        for (int ni = 0; ni < 2; ni++) {
#pragma unroll
            for (int j = 0; j < 4; j++) {
                int oc = w * 32 + mi * 16 + lg * 4 + j;
                int pxo = pxh * 32 + ni * 16 + r16;
                out[(size_t)(b * COUT + oc) * HW + y * WW + pxo] = acc[mi][ni][j] + bias[oc];
            }
        }
    }
}

extern "C" void kernel_launch(void* const* d_in, const int* in_sizes, int n_in,
                              void* d_out, int out_size, void* d_ws, size_t ws_size,
                              hipStream_t stream) {
    const float* x = (const float*)d_in[0];
    const float* extra_feat = (const float*)d_in[1];
    const float* weight = (const float*)d_in[2];
    const float* bias = (const float*)d_in[3];
    const float* off_w = (const float*)d_in[4];
    const float* off_b = (const float*)d_in[5];
    float* out = (float*)d_out;

    float* omP = (float*)d_ws;
    unsigned short* wpm = (unsigned short*)(omP + (size_t)BB * NCHUNK * HW * 4);
    unsigned short* wpo = wpm + (size_t)KTOT * COUT;
    unsigned short* xT = wpo + (size_t)KTOT * COUT;
    unsigned short* eT = xT + (size_t)BB * PH * PW * CC;

    pack_w_main<<<(KTOT * COUT) / 256, 256, 0, stream>>>(weight, wpm);
    pack_w_off<<<(KTOT * COUT) / 256, 256, 0, stream>>>(off_w, wpo);
    pad_tr2<<<dim3(BB * PH, 2), 256, 0, stream>>>(x, extra_feat, xT, eT);

    off_mfma<<<dim3(BB * HH, 2), 512, 0, stream>>>(eT, wpo, off_b, omP);
    dconv_mfma<<<dim3(BB * HH, 2), 512, 0, stream>>>(xT, omP, wpm, bias, out);
}

// Round 12
// 100.361 us; speedup vs baseline: 1.5760x; 1.1712x over previous
//
#include <hip/hip_runtime.h>
#include <hip/hip_bf16.h>
#include <math.h>

#define BB 4
#define CC 256
#define HH 64
#define WW 64
#define HW 4096
#define PH 68
#define PW 68
#define COUT 256
#define OFFC 216
#define KTOT 2304
#define NCHUNK 72

typedef __attribute__((ext_vector_type(4))) float f32x4;
typedef __attribute__((ext_vector_type(8))) short s16x8;
typedef __attribute__((ext_vector_type(8))) unsigned short u16x8;
typedef __attribute__((ext_vector_type(2))) unsigned int u32x2;
typedef __attribute__((ext_vector_type(4))) unsigned int u32x4;

__device__ __forceinline__ unsigned short f2bf(float f) {
    unsigned int u = __float_as_uint(f);
    return (unsigned short)((u + 0x7fffu + ((u >> 16) & 1u)) >> 16);
}
__device__ __forceinline__ float bflo(unsigned int u) { return __uint_as_float(u << 16); }
__device__ __forceinline__ float bfhi(unsigned int u) { return __uint_as_float(u & 0xffff0000u); }
__device__ __forceinline__ unsigned int pkbf(float a, float b) {
    __hip_bfloat162 h = __float22bfloat162_rn(make_float2(a, b));
    unsigned int r;
    __builtin_memcpy(&r, &h, 4);
    return r;
}

// barrier: LDS ordering only (all global loads are register-defined; compiler
// inserts its own counted vmcnt waits before uses). No sched_barrier pins (m141).
#define WAITL() asm volatile("s_waitcnt lgkmcnt(0)" ::: "memory")
#define RBAR() __builtin_amdgcn_s_barrier()

// ---------- pack main weight, k-swizzled per oc row (2-row granular)
__global__ __launch_bounds__(256) void pack_w_main(const float* __restrict__ w,
                                                   unsigned short* __restrict__ wp) {
    int idx = blockIdx.x * 256 + threadIdx.x;
    int t = idx >> 13, r = idx & 8191;
    int oc = r >> 5, s = (r >> 3) & 3, e = r & 7;
    int kk = ((s ^ ((oc >> 1) & 3)) << 3) | e;
    int dg = t / 9, tap = t - dg * 9;
    int c = dg * 32 + kk;
    wp[idx] = f2bf(w[((size_t)oc * CC + c) * 9 + tap]);
}

// ---------- pack offset weight (pad 216->256), t = tap*8+cg, same swizzle
__global__ __launch_bounds__(256) void pack_w_off(const float* __restrict__ w,
                                                  unsigned short* __restrict__ wp) {
    int idx = blockIdx.x * 256 + threadIdx.x;
    int t = idx >> 13, r = idx & 8191;
    int oc = r >> 5, s = (r >> 3) & 3, e = r & 7;
    int kk = ((s ^ ((oc >> 1) & 3)) << 3) | e;
    int tap = t >> 3, cg = t & 7;
    int c = cg * 32 + kk;
    float v = (oc < OFFC) ? w[((size_t)oc * CC + c) * 9 + tap] : 0.f;
    wp[idx] = f2bf(v);
}

// ---------- NCHW f32 -> padded NHWC bf16 (zero ring of 2), LDS-transposed coalesced
__global__ __launch_bounds__(256) void pad_tr2(const float* __restrict__ srcx,
                                               const float* __restrict__ srce,
                                               unsigned short* __restrict__ dx_,
                                               unsigned short* __restrict__ de_) {
    const float* src = blockIdx.y ? srce : srcx;
    unsigned short* dst = blockIdx.y ? de_ : dx_;
    int blk = blockIdx.x;
    int b = blk / PH, yp = blk % PH;
    int y = yp - 2;
    unsigned short* drow = dst + ((size_t)b * PH + yp) * PW * CC;
    int tid = threadIdx.x;
    if ((unsigned)y >= (unsigned)HH) {
        for (int i = tid; i < PW * CC / 8; i += 256) *(u16x8*)&drow[(size_t)i * 8] = (u16x8)0;
        return;
    }
    __shared__ float tile[64][65];
    int lane = tid & 63, w = tid >> 6;
    int oct = tid & 7, xi = tid >> 3;
    const float* srow = src + (size_t)b * CC * HW + (size_t)y * WW;
    for (int chunk = 0; chunk < 4; chunk++) {
        __syncthreads();
#pragma unroll
        for (int i = 0; i < 16; i++) {
            int c = chunk * 64 + w * 16 + i;
            tile[w * 16 + i][lane] = srow[(size_t)c * HW + lane];
        }
        __syncthreads();
#pragma unroll
        for (int xq = 0; xq < 3; xq++) {
            int xp = xq * 32 + xi;
            if (xp < PW) {
                int x = xp - 2;
                u16x8 v = (u16x8)0;
                if ((unsigned)x < (unsigned)WW) {
#pragma unroll
                    for (int e = 0; e < 8; e++) v[e] = f2bf(tile[oct * 8 + e][x]);
                }
                *(u16x8*)&drow[(size_t)xp * CC + chunk * 64 + oct * 8] = v;
            }
        }
    }
}

// ======================================================================
// GEMM geometry: block 512 thr = 8 waves, M=256 oc, N=32 px, K-step 64,
// grid (256 rows, 2 px-halves). A: global->VGPR per wave (fragment-ordered
// pack; loop-invariant lane offset; 1-iter prefetch pinned by asm barriers).
// B: sampled to LDS (dbuf, XOR swizzle, R9-verified 0 conflicts).
// ======================================================================

// aoff (per lane, loop-invariant): row = w*32 + r16, k-slot = lg ^ ((r16>>1)&3)
#define A_LOAD(WPP, T, AF)                                                \
    {                                                                     \
        const unsigned short* wt_ = WPP + (size_t)(T) * 8192 + aoff;      \
        AF[0] = *(const s16x8*)&wt_[0];                                   \
        AF[1] = *(const s16x8*)&wt_[512];                                 \
        AF[2] = *(const s16x8*)&wt_[8192];                                \
        AF[3] = *(const s16x8*)&wt_[8704];                                \
    }

#define MFMA8R(AC, BUF)                                                                      \
    {                                                                                        \
        int sw_ = (lg ^ ((r16 >> 1) & 3)) << 3;                                              \
        s16x8 b0_ = *(const s16x8*)&sB[BUF][0][r16 * 32 + sw_];                              \
        s16x8 b1_ = *(const s16x8*)&sB[BUF][0][(16 + r16) * 32 + sw_];                       \
        acc[0][0] = __builtin_amdgcn_mfma_f32_16x16x32_bf16(AC[0], b0_, acc[0][0], 0, 0, 0); \
        acc[0][1] = __builtin_amdgcn_mfma_f32_16x16x32_bf16(AC[0], b1_, acc[0][1], 0, 0, 0); \
        acc[1][0] = __builtin_amdgcn_mfma_f32_16x16x32_bf16(AC[1], b0_, acc[1][0], 0, 0, 0); \
        acc[1][1] = __builtin_amdgcn_mfma_f32_16x16x32_bf16(AC[1], b1_, acc[1][1], 0, 0, 0); \
        b0_ = *(const s16x8*)&sB[BUF][1][r16 * 32 + sw_];                                    \
        b1_ = *(const s16x8*)&sB[BUF][1][(16 + r16) * 32 + sw_];                             \
        acc[0][0] = __builtin_amdgcn_mfma_f32_16x16x32_bf16(AC[2], b0_, acc[0][0], 0, 0, 0); \
        acc[0][1] = __builtin_amdgcn_mfma_f32_16x16x32_bf16(AC[2], b1_, acc[0][1], 0, 0, 0); \
        acc[1][0] = __builtin_amdgcn_mfma_f32_16x16x32_bf16(AC[3], b0_, acc[1][0], 0, 0, 0); \
        acc[1][1] = __builtin_amdgcn_mfma_f32_16x16x32_bf16(AC[3], b1_, acc[1][1], 0, 0, 0); \
    }

// ======================================================================
// offset conv + fused prep epilogue
// ======================================================================
__global__ __launch_bounds__(512, 4) void off_mfma(const unsigned short* __restrict__ eT,
                                                   const unsigned short* __restrict__ wp,
                                                   const float* __restrict__ off_b,
                                                   float* __restrict__ omP) {
    __shared__ __align__(16) unsigned short sB[2][2][1024];
    __shared__ float sAcc[256 * 33];
    int bx = blockIdx.x;
    int b = bx >> 6, y = bx & 63;
    int pxh = blockIdx.y;
    int tid = threadIdx.x;
    int lane = tid & 63;
    int w = tid >> 6;
    int r16 = lane & 15, lg = lane >> 4;
    int px_l = tid >> 4, ch2 = tid & 15;
    int pxg = pxh * 32 + px_l;
    int aoff = (w * 32 + r16) * 32 + ((lg ^ ((r16 >> 1) & 3)) << 3);

    const unsigned short* eb = eT + (size_t)b * PH * PW * CC;

    f32x4 acc[2][2];
#pragma unroll
    for (int mi = 0; mi < 2; mi++)
#pragma unroll
        for (int ni = 0; ni < 2; ni++) acc[mi][ni] = (f32x4)0.f;

    s16x8 aA[4], aB[4];

#define BSLOT2 (px_l * 32 + ((((ch2 >> 2) ^ ((px_l >> 1) & 3))) << 3) + (ch2 & 3) * 2)
#define OF_B(T, BV)                                                                          \
    {                                                                                        \
        int tap_ = (T) >> 3, cg_ = (T) & 7;                                                  \
        int ky_ = tap_ / 3, kx_ = tap_ - ky_ * 3;                                            \
        BV = *(const unsigned int*)&eb[(size_t)((y + ky_ + 1) * PW + (pxg + kx_ + 1)) * CC + \
                                       cg_ * 32 + ch2 * 2];                                  \
    }
#define OF_ITF(T, BUF, AC, AN, BP0, BP1, BN0, BN1)               \
    {                                                            \
        A_LOAD(wp, (T) + 2, AN)                                  \
        OF_B((T) + 4, BN0)                                       \
        OF_B((T) + 5, BN1)                                       \
        MFMA8R(AC, BUF)                                          \
        *(unsigned int*)&sB[(BUF) ^ 1][0][BSLOT2] = BP0;         \
        *(unsigned int*)&sB[(BUF) ^ 1][1][BSLOT2] = BP1;         \
        WAITL();                                                 \
        RBAR();                                                  \
    }

    unsigned int bP0, bP1, bN0, bN1;
    {  // prologue
        A_LOAD(wp, 0, aA)
        unsigned int c0, c1;
        OF_B(0, c0)
        OF_B(1, c1)
        *(unsigned int*)&sB[0][0][BSLOT2] = c0;
        *(unsigned int*)&sB[0][1][BSLOT2] = c1;
        OF_B(2, bP0)
        OF_B(3, bP1)
        WAITL();
        RBAR();
    }
    for (int t = 0; t < 68; t += 4) {
        OF_ITF(t, 0, aA, aB, bP0, bP1, bN0, bN1)
        OF_ITF(t + 2, 1, aB, aA, bN0, bN1, bP0, bP1)
    }
    {  // T=68 tail: no more B loads; write last pair (70,71)
        A_LOAD(wp, 70, aB)
        MFMA8R(aA, 0)
        *(unsigned int*)&sB[1][0][BSLOT2] = bP0;
        *(unsigned int*)&sB[1][1][BSLOT2] = bP1;
        WAITL();
        RBAR();
    }
    MFMA8R(aB, 1)   // T=70

    // ---------- fused prep epilogue ----------
    __syncthreads();
#pragma unroll
    for (int mi = 0; mi < 2; mi++) {
#pragma unroll
        for (int ni = 0; ni < 2; ni++) {
#pragma unroll
            for (int j = 0; j < 4; j++) {
                int oc = w * 32 + mi * 16 + lg * 4 + j;
                float bv = (oc < OFFC) ? off_b[oc] : 0.f;
                sAcc[oc * 33 + ni * 16 + r16] = acc[mi][ni][j] + bv;
            }
        }
    }
    __syncthreads();
    float* omPb = omP + (size_t)b * NCHUNK * HW * 4;
    for (int i = tid; i < NCHUNK * 32; i += 512) {
        int tt = i >> 5, px = i & 31;
        int dg = (tt * 57) >> 9;
        int tap = tt - dg * 9;
        int ky = tap / 3, kx = tap - ky * 3;
        float dyv = sAcc[(dg * 18 + 2 * tap) * 33 + px];
        float dxv = sAcc[(dg * 18 + 2 * tap + 1) * 33 + px];
        float mr = sAcc[(144 + dg * 9 + tap) * 33 + px];
        int xg = pxh * 32 + px;
        float mv = 1.f / (1.f + __expf(-mr));
        float py = (float)(y + ky - 1) + dyv;
        float pxx = (float)(xg + kx - 1) + dxv;
        float y0f = floorf(py), x0f = floorf(pxx);
        float fy = py - y0f, fx = pxx - x0f;
        int yp0 = min(max((int)y0f + 2, 0), PH - 1);
        int yp1 = min(max((int)y0f + 3, 0), PH - 1);
        int xp0 = min(max((int)x0f + 2, 0), PW - 1);
        int xp1 = min(max((int)x0f + 3, 0), PW - 1);
        unsigned int iv = (unsigned int)(yp0 * PW + xp0) | ((unsigned int)(xp1 - xp0) << 13) |
                          ((unsigned int)(yp1 - yp0) << 14);
        float w00 = (1.f - fy) * (1.f - fx) * mv;
        float w01 = (1.f - fy) * fx * mv;
        float w10 = fy * (1.f - fx) * mv;
        float w11 = fy * fx * mv;
        u32x4 o;
        o[0] = iv;
        o[1] = pkbf(w00, w01);
        o[2] = pkbf(w10, w11);
        o[3] = 0;
        *(u32x4*)(omPb + ((size_t)tt * HW + y * WW + xg) * 4) = o;
    }
}

// ======================================================================
// fused deformable sampling + main conv
// ======================================================================
__global__ __launch_bounds__(512, 4) void dconv_mfma(const unsigned short* __restrict__ xT,
                                                     const float* __restrict__ omP,
                                                     const unsigned short* __restrict__ wp,
                                                     const float* __restrict__ bias,
                                                     float* __restrict__ out) {
    __shared__ __align__(16) unsigned short sB[2][2][1024];
    int bx = blockIdx.x;
    int b = bx >> 6, y = bx & 63;
    int pxh = blockIdx.y;
    int tid = threadIdx.x;
    int lane = tid & 63;
    int w = tid >> 6;
    int r16 = lane & 15, lg = lane >> 4;
    int kt = tid >> 8;
    int px_l = (tid >> 3) & 31;
    int ch4 = tid & 7;
    int yx = y * WW + pxh * 32 + px_l;
    int aoff = (w * 32 + r16) * 32 + ((lg ^ ((r16 >> 1) & 3)) << 3);

    const unsigned short* xb = xT + (size_t)b * PH * PW * CC;
    const float* omPb = omP + (size_t)b * NCHUNK * HW * 4;

    f32x4 acc[2][2];
#pragma unroll
    for (int mi = 0; mi < 2; mi++)
#pragma unroll
        for (int ni = 0; ni < 2; ni++) acc[mi][ni] = (f32x4)0.f;

    s16x8 aA[4], aB[4];

#define BSLOT4 (px_l * 32 + ((((ch4 >> 1) ^ ((px_l >> 1) & 3))) << 3) + (ch4 & 1) * 4)
#define DC_OML(T) (*(const u32x4*)(omPb + ((size_t)(T)*HW + yx) * 4))

#define DC_G(T, OM, G00, G01, G10, G11)                                   \
    {                                                                     \
        int dg_ = ((T) * 57) >> 9;                                        \
        unsigned int iv_ = OM[0];                                         \
        int o00_ = (int)(iv_ & 8191u) << 8;                               \
        int dxe_ = (int)((iv_ >> 13) & 1u) << 8;                          \
        int dye_ = ((iv_ >> 14) & 1u) ? (PW * CC) : 0;                    \
        const unsigned short* p_ = xb + dg_ * 32 + ch4 * 4;               \
        G00 = *(const u32x2*)(p_ + o00_);                                 \
        G01 = *(const u32x2*)(p_ + o00_ + dxe_);                          \
        G10 = *(const u32x2*)(p_ + o00_ + dye_);                          \
        G11 = *(const u32x2*)(p_ + o00_ + dye_ + dxe_);                   \
    }
#define DC_FIN(OM, G00, G01, G10, G11, BUF)                                               \
    {                                                                                     \
        float w00 = bflo(OM[1]), w01 = bfhi(OM[1]);                                       \
        float w10 = bflo(OM[2]), w11 = bfhi(OM[2]);                                       \
        float v0 = w00 * bflo(G00[0]) + w01 * bflo(G01[0]) + w10 * bflo(G10[0]) +         \
                   w11 * bflo(G11[0]);                                                    \
        float v1 = w00 * bfhi(G00[0]) + w01 * bfhi(G01[0]) + w10 * bfhi(G10[0]) +         \
                   w11 * bfhi(G11[0]);                                                    \
        float v2 = w00 * bflo(G00[1]) + w01 * bflo(G01[1]) + w10 * bflo(G10[1]) +         \
                   w11 * bflo(G11[1]);                                                    \
        float v3 = w00 * bfhi(G00[1]) + w01 * bfhi(G01[1]) + w10 * bfhi(G10[1]) +         \
                   w11 * bfhi(G11[1]);                                                    \
        u32x2 pk_;                                                                        \
        pk_[0] = pkbf(v0, v1);                                                            \
        pk_[1] = pkbf(v2, v3);                                                            \
        *(u32x2*)&sB[BUF][kt][BSLOT4] = pk_;                                              \
    }
#define DC_ITF(T, BUF, AC, AN, GP0, GP1, GP2, GP3, GN0, GN1, GN2, GN3, SF, SG) \
    {                                                                          \
        A_LOAD(wp, (T) + 2, AN)                                                \
        DC_G((T) + 4 + kt, SG, GN0, GN1, GN2, GN3)                             \
        MFMA8R(AC, BUF)                                                        \
        DC_FIN(SF, GP0, GP1, GP2, GP3, (BUF) ^ 1)                              \
        SF = DC_OML((T) + 6 + kt);                                             \
        WAITL();                                                               \
        RBAR();                                                                \
    }

    u32x4 omA, omB;
    u32x2 gA0, gA1, gA2, gA3, gB0, gB1, gB2, gB3;
    {  // prologue
        A_LOAD(wp, 0, aA)
        u32x4 om0 = DC_OML(kt);
        omA = DC_OML(2 + kt);
        u32x2 t0, t1, t2, t3;
        DC_G(kt, om0, t0, t1, t2, t3)
        DC_FIN(om0, t0, t1, t2, t3, 0)
        DC_G(2 + kt, omA, gA0, gA1, gA2, gA3)
        omB = DC_OML(4 + kt);
        WAITL();
        RBAR();
    }
    for (int t = 0; t < 64; t += 4) {
        DC_ITF(t, 0, aA, aB, gA0, gA1, gA2, gA3, gB0, gB1, gB2, gB3, omA, omB)
        DC_ITF(t + 2, 1, aB, aA, gB0, gB1, gB2, gB3, gA0, gA1, gA2, gA3, omB, omA)
    }
    DC_ITF(64, 0, aA, aB, gA0, gA1, gA2, gA3, gB0, gB1, gB2, gB3, omA, omB)
    {  // T=66: no om load (T+6 out of range)
        A_LOAD(wp, 68, aA)
        DC_G(70 + kt, omA, gA0, gA1, gA2, gA3)
        MFMA8R(aB, 1)
        DC_FIN(omB, gB0, gB1, gB2, gB3, 0)
        WAITL();
        RBAR();
    }
    {  // T=68: no gather, no om
        A_LOAD(wp, 70, aB)
        MFMA8R(aA, 0)
        DC_FIN(omA, gA0, gA1, gA2, gA3, 1)
        WAITL();
        RBAR();
    }
    MFMA8R(aB, 1)   // T=70

#pragma unroll
    for (int mi = 0; mi < 2; mi++) {
#pragma unroll
        for (int ni = 0; ni < 2; ni++) {
#pragma unroll
            for (int j = 0; j < 4; j++) {
                int oc = w * 32 + mi * 16 + lg * 4 + j;
                int pxo = pxh * 32 + ni * 16 + r16;
                out[(size_t)(b * COUT + oc) * HW + y * WW + pxo] = acc[mi][ni][j] + bias[oc];
            }
        }
    }
}

extern "C" void kernel_launch(void* const* d_in, const int* in_sizes, int n_in,
                              void* d_out, int out_size, void* d_ws, size_t ws_size,
                              hipStream_t stream) {
    const float* x = (const float*)d_in[0];
    const float* extra_feat = (const float*)d_in[1];
    const float* weight = (const float*)d_in[2];
    const float* bias = (const float*)d_in[3];
    const float* off_w = (const float*)d_in[4];
    const float* off_b = (const float*)d_in[5];
    float* out = (float*)d_out;

    float* omP = (float*)d_ws;
    unsigned short* wpm = (unsigned short*)(omP + (size_t)BB * NCHUNK * HW * 4);
    unsigned short* wpo = wpm + (size_t)KTOT * COUT;
    unsigned short* xT = wpo + (size_t)KTOT * COUT;
    unsigned short* eT = xT + (size_t)BB * PH * PW * CC;

    pack_w_main<<<(KTOT * COUT) / 256, 256, 0, stream>>>(weight, wpm);
    pack_w_off<<<(KTOT * COUT) / 256, 256, 0, stream>>>(off_w, wpo);
    pad_tr2<<<dim3(BB * PH, 2), 256, 0, stream>>>(x, extra_feat, xT, eT);

    off_mfma<<<dim3(BB * HH, 2), 512, 0, stream>>>(eT, wpo, off_b, omP);
    dconv_mfma<<<dim3(BB * HH, 2), 512, 0, stream>>>(xT, omP, wpm, bias, out);
}

// Round 13
// 89.736 us; speedup vs baseline: 1.7626x; 1.1184x over previous
//
#include <hip/hip_runtime.h>
#include <hip/hip_bf16.h>
#include <math.h>

#define BB 4
#define CC 256
#define HH 64
#define WW 64
#define HW 4096
#define PH 68
#define PW 68
#define COUT 256
#define OFFC 216
#define KTOT 2304
#define NCHUNK 72

typedef __attribute__((ext_vector_type(4))) float f32x4;
typedef __attribute__((ext_vector_type(8))) short s16x8;
typedef __attribute__((ext_vector_type(8))) unsigned short u16x8;
typedef __attribute__((ext_vector_type(2))) unsigned int u32x2;
typedef __attribute__((ext_vector_type(4))) unsigned int u32x4;

__device__ __forceinline__ unsigned short f2bf(float f) {
    unsigned int u = __float_as_uint(f);
    return (unsigned short)((u + 0x7fffu + ((u >> 16) & 1u)) >> 16);
}
__device__ __forceinline__ float bflo(unsigned int u) { return __uint_as_float(u << 16); }
__device__ __forceinline__ float bfhi(unsigned int u) { return __uint_as_float(u & 0xffff0000u); }
__device__ __forceinline__ unsigned int pkbf(float a, float b) {
    __hip_bfloat162 h = __float22bfloat162_rn(make_float2(a, b));
    unsigned int r;
    __builtin_memcpy(&r, &h, 4);
    return r;
}

#define WAITL() asm volatile("s_waitcnt lgkmcnt(0)" ::: "memory")
#define RBAR() __builtin_amdgcn_s_barrier()

// ---------- pack main weight, k-swizzled per oc row (2-row granular)
__global__ __launch_bounds__(256) void pack_w_main(const float* __restrict__ w,
                                                   unsigned short* __restrict__ wp) {
    int idx = blockIdx.x * 256 + threadIdx.x;
    int t = idx >> 13, r = idx & 8191;
    int oc = r >> 5, s = (r >> 3) & 3, e = r & 7;
    int kk = ((s ^ ((oc >> 1) & 3)) << 3) | e;
    int dg = t / 9, tap = t - dg * 9;
    int c = dg * 32 + kk;
    wp[idx] = f2bf(w[((size_t)oc * CC + c) * 9 + tap]);
}

// ---------- pack offset weight (pad 216->256), t = tap*8+cg, same swizzle
__global__ __launch_bounds__(256) void pack_w_off(const float* __restrict__ w,
                                                  unsigned short* __restrict__ wp) {
    int idx = blockIdx.x * 256 + threadIdx.x;
    int t = idx >> 13, r = idx & 8191;
    int oc = r >> 5, s = (r >> 3) & 3, e = r & 7;
    int kk = ((s ^ ((oc >> 1) & 3)) << 3) | e;
    int tap = t >> 3, cg = t & 7;
    int c = cg * 32 + kk;
    float v = (oc < OFFC) ? w[((size_t)oc * CC + c) * 9 + tap] : 0.f;
    wp[idx] = f2bf(v);
}

// ---------- NCHW f32 -> padded NHWC bf16 (zero ring of 2), LDS-transposed coalesced
__global__ __launch_bounds__(256) void pad_tr2(const float* __restrict__ srcx,
                                               const float* __restrict__ srce,
                                               unsigned short* __restrict__ dx_,
                                               unsigned short* __restrict__ de_) {
    const float* src = blockIdx.y ? srce : srcx;
    unsigned short* dst = blockIdx.y ? de_ : dx_;
    int blk = blockIdx.x;
    int b = blk / PH, yp = blk % PH;
    int y = yp - 2;
    unsigned short* drow = dst + ((size_t)b * PH + yp) * PW * CC;
    int tid = threadIdx.x;
    if ((unsigned)y >= (unsigned)HH) {
        for (int i = tid; i < PW * CC / 8; i += 256) *(u16x8*)&drow[(size_t)i * 8] = (u16x8)0;
        return;
    }
    __shared__ float tile[64][65];
    int lane = tid & 63, w = tid >> 6;
    int oct = tid & 7, xi = tid >> 3;
    const float* srow = src + (size_t)b * CC * HW + (size_t)y * WW;
    for (int chunk = 0; chunk < 4; chunk++) {
        __syncthreads();
#pragma unroll
        for (int i = 0; i < 16; i++) {
            int c = chunk * 64 + w * 16 + i;
            tile[w * 16 + i][lane] = srow[(size_t)c * HW + lane];
        }
        __syncthreads();
#pragma unroll
        for (int xq = 0; xq < 3; xq++) {
            int xp = xq * 32 + xi;
            if (xp < PW) {
                int x = xp - 2;
                u16x8 v = (u16x8)0;
                if ((unsigned)x < (unsigned)WW) {
#pragma unroll
                    for (int e = 0; e < 8; e++) v[e] = f2bf(tile[oct * 8 + e][x]);
                }
                *(u16x8*)&drow[(size_t)xp * CC + chunk * 64 + oct * 8] = v;
            }
        }
    }
}

// ======================================================================
// FUSED kernel: per (row y, px-half): phase1 offset GEMM -> prep in LDS ->
// phase2 main GEMM with deformable sampling. Geometry as R12 (verified):
// block 512 thr = 8 waves, M=256 oc, N=32 px, K-step 64; A global->VGPR;
// B in dbuf LDS, XOR swizzle (0 conflicts, R9).
// ======================================================================

#define A_LOAD(WPP, T, AF)                                                \
    {                                                                     \
        const unsigned short* wt_ = WPP + (size_t)(T) * 8192 + aoff;      \
        AF[0] = *(const s16x8*)&wt_[0];                                   \
        AF[1] = *(const s16x8*)&wt_[512];                                 \
        AF[2] = *(const s16x8*)&wt_[8192];                                \
        AF[3] = *(const s16x8*)&wt_[8704];                                \
    }

#define MFMA8R(AC, BUF)                                                                      \
    {                                                                                        \
        int sw_ = (lg ^ ((r16 >> 1) & 3)) << 3;                                              \
        s16x8 b0_ = *(const s16x8*)&sB[BUF][0][r16 * 32 + sw_];                              \
        s16x8 b1_ = *(const s16x8*)&sB[BUF][0][(16 + r16) * 32 + sw_];                       \
        acc[0][0] = __builtin_amdgcn_mfma_f32_16x16x32_bf16(AC[0], b0_, acc[0][0], 0, 0, 0); \
        acc[0][1] = __builtin_amdgcn_mfma_f32_16x16x32_bf16(AC[0], b1_, acc[0][1], 0, 0, 0); \
        acc[1][0] = __builtin_amdgcn_mfma_f32_16x16x32_bf16(AC[1], b0_, acc[1][0], 0, 0, 0); \
        acc[1][1] = __builtin_amdgcn_mfma_f32_16x16x32_bf16(AC[1], b1_, acc[1][1], 0, 0, 0); \
        b0_ = *(const s16x8*)&sB[BUF][1][r16 * 32 + sw_];                                    \
        b1_ = *(const s16x8*)&sB[BUF][1][(16 + r16) * 32 + sw_];                             \
        acc[0][0] = __builtin_amdgcn_mfma_f32_16x16x32_bf16(AC[2], b0_, acc[0][0], 0, 0, 0); \
        acc[0][1] = __builtin_amdgcn_mfma_f32_16x16x32_bf16(AC[2], b1_, acc[0][1], 0, 0, 0); \
        acc[1][0] = __builtin_amdgcn_mfma_f32_16x16x32_bf16(AC[3], b0_, acc[1][0], 0, 0, 0); \
        acc[1][1] = __builtin_amdgcn_mfma_f32_16x16x32_bf16(AC[3], b1_, acc[1][1], 0, 0, 0); \
    }

__global__ __launch_bounds__(512, 4) void fused_dcn(const unsigned short* __restrict__ eT,
                                                    const unsigned short* __restrict__ xT,
                                                    const unsigned short* __restrict__ wpo,
                                                    const unsigned short* __restrict__ wpm,
                                                    const float* __restrict__ off_b,
                                                    const float* __restrict__ bias,
                                                    float* __restrict__ out) {
    __shared__ __align__(16) unsigned short sB[2][2][1024];     // 8 KB
    __shared__ __align__(16) unsigned int prep[NCHUNK][32][3];  // 27 KB
    __shared__ float sAcc[OFFC * 33];                           // 28.5 KB

    int bx = blockIdx.x;
    int b = bx >> 6, y = bx & 63;
    int pxh = blockIdx.y;
    int tid = threadIdx.x;
    int lane = tid & 63;
    int w = tid >> 6;
    int r16 = lane & 15, lg = lane >> 4;
    int aoff = (w * 32 + r16) * 32 + ((lg ^ ((r16 >> 1) & 3)) << 3);
    // phase-1 B-stage thread map
    int p1px = tid >> 4, ch2 = tid & 15;
    int pxg = pxh * 32 + p1px;
    // phase-2 sample thread map
    int kt = tid >> 8;
    int p2px = (tid >> 3) & 31;
    int ch4 = tid & 7;

    const unsigned short* eb = eT + (size_t)b * PH * PW * CC;
    const unsigned short* xb = xT + (size_t)b * PH * PW * CC;

    f32x4 acc[2][2];
#pragma unroll
    for (int mi = 0; mi < 2; mi++)
#pragma unroll
        for (int ni = 0; ni < 2; ni++) acc[mi][ni] = (f32x4)0.f;

    s16x8 aA[4], aB[4];

    // =================== phase 1: offset GEMM ===================
#define BSLOT2 (p1px * 32 + ((((ch2 >> 2) ^ ((p1px >> 1) & 3))) << 3) + (ch2 & 3) * 2)
#define OF_B(T, BV)                                                                          \
    {                                                                                        \
        int tap_ = (T) >> 3, cg_ = (T) & 7;                                                  \
        int ky_ = tap_ / 3, kx_ = tap_ - ky_ * 3;                                            \
        BV = *(const unsigned int*)&eb[(size_t)((y + ky_ + 1) * PW + (pxg + kx_ + 1)) * CC + \
                                       cg_ * 32 + ch2 * 2];                                  \
    }
#define OF_ITF(T, BUF, AC, AN, BP0, BP1, BN0, BN1)               \
    {                                                            \
        A_LOAD(wpo, (T) + 2, AN)                                 \
        OF_B((T) + 4, BN0)                                       \
        OF_B((T) + 5, BN1)                                       \
        MFMA8R(AC, BUF)                                          \
        *(unsigned int*)&sB[(BUF) ^ 1][0][BSLOT2] = BP0;         \
        *(unsigned int*)&sB[(BUF) ^ 1][1][BSLOT2] = BP1;         \
        WAITL();                                                 \
        RBAR();                                                  \
    }

    {
        unsigned int bP0, bP1, bN0, bN1;
        {  // prologue
            A_LOAD(wpo, 0, aA)
            unsigned int c0, c1;
            OF_B(0, c0)
            OF_B(1, c1)
            *(unsigned int*)&sB[0][0][BSLOT2] = c0;
            *(unsigned int*)&sB[0][1][BSLOT2] = c1;
            OF_B(2, bP0)
            OF_B(3, bP1)
            WAITL();
            RBAR();
        }
        for (int t = 0; t < 68; t += 4) {
            OF_ITF(t, 0, aA, aB, bP0, bP1, bN0, bN1)
            OF_ITF(t + 2, 1, aB, aA, bN0, bN1, bP0, bP1)
        }
        {  // T=68 tail
            A_LOAD(wpo, 70, aB)
            MFMA8R(aA, 0)
            *(unsigned int*)&sB[1][0][BSLOT2] = bP0;
            *(unsigned int*)&sB[1][1][BSLOT2] = bP1;
            WAITL();
            RBAR();
        }
        MFMA8R(aB, 1)  // T=70
    }

    // =================== prep: acc -> {idx, w01, w23} in LDS ===================
    __syncthreads();
#pragma unroll
    for (int mi = 0; mi < 2; mi++) {
#pragma unroll
        for (int ni = 0; ni < 2; ni++) {
#pragma unroll
            for (int j = 0; j < 4; j++) {
                int oc = w * 32 + mi * 16 + lg * 4 + j;
                if (oc < OFFC) sAcc[oc * 33 + ni * 16 + r16] = acc[mi][ni][j] + off_b[oc];
            }
        }
    }
    __syncthreads();
    for (int i = tid; i < NCHUNK * 32; i += 512) {
        int tt = i >> 5, px = i & 31;
        int dg = (tt * 57) >> 9;
        int tap = tt - dg * 9;
        int ky = tap / 3, kx = tap - ky * 3;
        float dyv = sAcc[(dg * 18 + 2 * tap) * 33 + px];
        float dxv = sAcc[(dg * 18 + 2 * tap + 1) * 33 + px];
        float mr = sAcc[(144 + dg * 9 + tap) * 33 + px];
        int xg = pxh * 32 + px;
        float mv = 1.f / (1.f + __expf(-mr));
        float py = (float)(y + ky - 1) + dyv;
        float pxx = (float)(xg + kx - 1) + dxv;
        float y0f = floorf(py), x0f = floorf(pxx);
        float fy = py - y0f, fx = pxx - x0f;
        int yp0 = min(max((int)y0f + 2, 0), PH - 1);
        int yp1 = min(max((int)y0f + 3, 0), PH - 1);
        int xp0 = min(max((int)x0f + 2, 0), PW - 1);
        int xp1 = min(max((int)x0f + 3, 0), PW - 1);
        prep[tt][px][0] = (unsigned int)(yp0 * PW + xp0) | ((unsigned int)(xp1 - xp0) << 13) |
                          ((unsigned int)(yp1 - yp0) << 14);
        float w00 = (1.f - fy) * (1.f - fx) * mv;
        float w01 = (1.f - fy) * fx * mv;
        float w10 = fy * (1.f - fx) * mv;
        float w11 = fy * fx * mv;
        prep[tt][px][1] = pkbf(w00, w01);
        prep[tt][px][2] = pkbf(w10, w11);
    }
    __syncthreads();

    // =================== phase 2: main GEMM + sampling ===================
#pragma unroll
    for (int mi = 0; mi < 2; mi++)
#pragma unroll
        for (int ni = 0; ni < 2; ni++) acc[mi][ni] = (f32x4)0.f;

#define BSLOT4 (p2px * 32 + ((((ch4 >> 1) ^ ((p2px >> 1) & 3))) << 3) + (ch4 & 1) * 4)
#define DC_G(T, G00, G01, G10, G11)                                       \
    {                                                                     \
        int dg_ = ((T) * 57) >> 9;                                        \
        unsigned int iv_ = prep[T][p2px][0];                              \
        int o00_ = (int)(iv_ & 8191u) << 8;                               \
        int dxe_ = (int)((iv_ >> 13) & 1u) << 8;                          \
        int dye_ = ((iv_ >> 14) & 1u) ? (PW * CC) : 0;                    \
        const unsigned short* p_ = xb + dg_ * 32 + ch4 * 4;               \
        G00 = *(const u32x2*)(p_ + o00_);                                 \
        G01 = *(const u32x2*)(p_ + o00_ + dxe_);                          \
        G10 = *(const u32x2*)(p_ + o00_ + dye_);                          \
        G11 = *(const u32x2*)(p_ + o00_ + dye_ + dxe_);                   \
    }
#define DC_FIN(T, G00, G01, G10, G11, BUF)                                                \
    {                                                                                     \
        unsigned int wa_ = prep[T][p2px][1];                                              \
        unsigned int wb_ = prep[T][p2px][2];                                              \
        float w00 = bflo(wa_), w01 = bfhi(wa_);                                           \
        float w10 = bflo(wb_), w11 = bfhi(wb_);                                           \
        float v0 = w00 * bflo(G00[0]) + w01 * bflo(G01[0]) + w10 * bflo(G10[0]) +         \
                   w11 * bflo(G11[0]);                                                    \
        float v1 = w00 * bfhi(G00[0]) + w01 * bfhi(G01[0]) + w10 * bfhi(G10[0]) +         \
                   w11 * bfhi(G11[0]);                                                    \
        float v2 = w00 * bflo(G00[1]) + w01 * bflo(G01[1]) + w10 * bflo(G10[1]) +         \
                   w11 * bflo(G11[1]);                                                    \
        float v3 = w00 * bfhi(G00[1]) + w01 * bfhi(G01[1]) + w10 * bfhi(G10[1]) +         \
                   w11 * bfhi(G11[1]);                                                    \
        u32x2 pk_;                                                                        \
        pk_[0] = pkbf(v0, v1);                                                            \
        pk_[1] = pkbf(v2, v3);                                                            \
        *(u32x2*)&sB[BUF][kt][BSLOT4] = pk_;                                              \
    }
#define DC_ITF(T, BUF, AC, AN, GP0, GP1, GP2, GP3, GN0, GN1, GN2, GN3)     \
    {                                                                      \
        A_LOAD(wpm, (T) + 2, AN)                                           \
        DC_G((T) + 4 + kt, GN0, GN1, GN2, GN3)                             \
        MFMA8R(AC, BUF)                                                    \
        DC_FIN((T) + 2 + kt, GP0, GP1, GP2, GP3, (BUF) ^ 1)                \
        WAITL();                                                           \
        RBAR();                                                            \
    }

    {
        u32x2 gA0, gA1, gA2, gA3, gB0, gB1, gB2, gB3;
        {  // prologue
            A_LOAD(wpm, 0, aA)
            u32x2 t0, t1, t2, t3;
            DC_G(kt, t0, t1, t2, t3)
            DC_FIN(kt, t0, t1, t2, t3, 0)
            DC_G(2 + kt, gA0, gA1, gA2, gA3)
            WAITL();
            RBAR();
        }
        for (int t = 0; t < 64; t += 4) {
            DC_ITF(t, 0, aA, aB, gA0, gA1, gA2, gA3, gB0, gB1, gB2, gB3)
            DC_ITF(t + 2, 1, aB, aA, gB0, gB1, gB2, gB3, gA0, gA1, gA2, gA3)
        }
        DC_ITF(64, 0, aA, aB, gA0, gA1, gA2, gA3, gB0, gB1, gB2, gB3)
        DC_ITF(66, 1, aB, aA, gB0, gB1, gB2, gB3, gA0, gA1, gA2, gA3)
        {  // T=68: no more gathers to issue
            A_LOAD(wpm, 70, aB)
            MFMA8R(aA, 0)
            DC_FIN(70 + kt, gA0, gA1, gA2, gA3, 1)
            WAITL();
            RBAR();
        }
        MFMA8R(aB, 1)  // T=70
    }

#pragma unroll
    for (int mi = 0; mi < 2; mi++) {
#pragma unroll
        for (int ni = 0; ni < 2; ni++) {
#pragma unroll
            for (int j = 0; j < 4; j++) {
                int oc = w * 32 + mi * 16 + lg * 4 + j;
                int pxo = pxh * 32 + ni * 16 + r16;
                out[(size_t)(b * COUT + oc) * HW + y * WW + pxo] = acc[mi][ni][j] + bias[oc];
            }
        }
    }
}

extern "C" void kernel_launch(void* const* d_in, const int* in_sizes, int n_in,
                              void* d_out, int out_size, void* d_ws, size_t ws_size,
                              hipStream_t stream) {
    const float* x = (const float*)d_in[0];
    const float* extra_feat = (const float*)d_in[1];
    const float* weight = (const float*)d_in[2];
    const float* bias = (const float*)d_in[3];
    const float* off_w = (const float*)d_in[4];
    const float* off_b = (const float*)d_in[5];
    float* out = (float*)d_out;

    unsigned short* wpm = (unsigned short*)d_ws;            // 1.18 MB
    unsigned short* wpo = wpm + (size_t)KTOT * COUT;        // 1.18 MB
    unsigned short* xT = wpo + (size_t)KTOT * COUT;         // 9.05 MB
    unsigned short* eT = xT + (size_t)BB * PH * PW * CC;    // 9.05 MB

    pack_w_main<<<(KTOT * COUT) / 256, 256, 0, stream>>>(weight, wpm);
    pack_w_off<<<(KTOT * COUT) / 256, 256, 0, stream>>>(off_w, wpo);
    pad_tr2<<<dim3(BB * PH, 2), 256, 0, stream>>>(x, extra_feat, xT, eT);

    fused_dcn<<<dim3(BB * HH, 2), 512, 0, stream>>>(eT, xT, wpo, wpm, off_b, bias, out);
}